// Round 12
// baseline (163.812 us; speedup 1.0000x reference)
//
#include <hip/hip_runtime.h>

#define H 16
#define N 2048
#define E 64
#define D 1024

typedef __attribute__((ext_vector_type(8))) short bf16x8;
typedef __attribute__((ext_vector_type(4))) float f32x4;
typedef __attribute__((ext_vector_type(4))) unsigned int u32x4;

__device__ __forceinline__ float bf2f(unsigned short u) {
    union { unsigned int i; float f; } v;
    v.i = ((unsigned int)u) << 16;
    return v.f;
}
__device__ __forceinline__ unsigned short f2bf(float f) {
    unsigned int u = __float_as_uint(f);
    return (unsigned short)((u + 0x7fffu + ((u >> 16) & 1u)) >> 16);
}
// v_cvt_pk_bf16_f32: D.lo = bf16(lo), D.hi = bf16(hi)
__device__ __forceinline__ unsigned int cvtpk(float lo, float hi) {
    unsigned int r;
    asm("v_cvt_pk_bf16_f32 %0, %1, %2" : "=v"(r) : "v"(lo), "v"(hi));
    return r;
}
__device__ __forceinline__ bf16x8 pk4(unsigned int a, unsigned int b,
                                      unsigned int c, unsigned int d) {
    union { u32x4 u; bf16x8 h; } x;
    x.u = (u32x4){a, b, c, d};
    return x.h;
}
// bare hardware exp2: v_exp_f32 computes D = 2^S0 (one transcendental op;
// exp2f() would lower to the precise OCML routine, ~6 ops -- measured R6)
__device__ __forceinline__ float ex2(float x) {
    float r;
    asm("v_exp_f32 %0, %1" : "=v"(r) : "v"(x));
    return r;
}
#define MFMA(a, b, c) __builtin_amdgcn_mfma_f32_16x16x32_bf16(a, b, c, 0, 0, 0)

// async global->LDS, 16B per lane. LDS dest must be base+lane*16 contiguous.
typedef __attribute__((address_space(3))) unsigned int lds_u32;
typedef const __attribute__((address_space(1))) unsigned int glb_u32;
__device__ __forceinline__ void dma16(const unsigned short* g, unsigned short* l) {
    __builtin_amdgcn_global_load_lds((glb_u32*)g, (lds_u32*)l, 16, 0, 0);
}

// XOR-swizzled LDS tiles (16B chunk granularity): physical chunk = c ^ (row&7).
__device__ __forceinline__ int sw8(int row, int c)  { return row * 64  + ((c ^ (row & 7)) << 3); }
__device__ __forceinline__ int sw16(int row, int c) { return row * 128 + ((c ^ (row & 7)) << 3); }

// ---------------------------------------------------------------------------
// K1: merged converts. blocks [0,2048): x fp32 -> xh/xl.
// blocks [2048,3072): weights. q -> wBh/wBl rows [0,1024); k -> rows
// [1024,2048); v -> wvt [h*64+e][d] (hi only); o -> woh [c][d] (hi only).
// ---------------------------------------------------------------------------
__global__ __launch_bounds__(256) void convert_all_kernel(
    const float* __restrict__ x,
    const float* __restrict__ qw, const float* __restrict__ kw,
    const float* __restrict__ vw, const float* __restrict__ ow,
    unsigned short* __restrict__ xh, unsigned short* __restrict__ xl,
    unsigned short* __restrict__ wBh, unsigned short* __restrict__ wBl,
    unsigned short* __restrict__ wvt, unsigned short* __restrict__ woh)
{
    __shared__ float ts[64][65];
    const int b0 = blockIdx.x;
    const int t = threadIdx.x;
    if (b0 < 2048) {
        const int i = (b0 * 256 + t) * 4;
        const float4 v = *(const float4*)&x[i];
        ushort4 hh, ll;
        hh.x = f2bf(v.x); ll.x = f2bf(v.x - bf2f(hh.x));
        hh.y = f2bf(v.y); ll.y = f2bf(v.y - bf2f(hh.y));
        hh.z = f2bf(v.z); ll.z = f2bf(v.z - bf2f(hh.z));
        hh.w = f2bf(v.w); ll.w = f2bf(v.w - bf2f(hh.w));
        *(ushort4*)&xh[i] = hh;
        *(ushort4*)&xl[i] = ll;
        return;
    }
    const int b = b0 - 2048;
    const float* src;
    int rs, dt, orow0;
    bool has_lo;
    unsigned short *dh, *dl;
    if (b < 768) {
        const int which = b >> 8, r = b & 255, h = r >> 4;
        dt = r & 15;
        src = (which == 0 ? qw : which == 1 ? kw : vw) + ((size_t)h * D + dt * 64) * E;
        rs = E;
        if (which == 0)      { dh = wBh; dl = wBl; orow0 = h * 64;        has_lo = true; }
        else if (which == 1) { dh = wBh; dl = wBl; orow0 = 1024 + h * 64; has_lo = true; }
        else                 { dh = wvt; dl = wBl; orow0 = h * 64;        has_lo = false; }
    } else {
        const int r = b - 768, ct = r >> 4;
        dt = r & 15;
        src = ow + (size_t)(dt * 64) * D + ct * 64;
        rs = D;
        orow0 = ct * 64;
        dh = woh; dl = wBl; has_lo = false;   // o: hi only
    }
    {
        const int row = t >> 2, cb = (t & 3) * 16;
        #pragma unroll
        for (int j = 0; j < 16; j += 4) {
            const float4 v = *(const float4*)&src[row * rs + cb + j];
            ts[row][cb + j + 0] = v.x;
            ts[row][cb + j + 1] = v.y;
            ts[row][cb + j + 2] = v.z;
            ts[row][cb + j + 3] = v.w;
        }
    }
    __syncthreads();
    {
        const int cl = t >> 2, dp = (t & 3) * 16;
        bf16x8 hv0, hv1, lv0, lv1;
        #pragma unroll
        for (int i = 0; i < 16; ++i) {
            const float f = ts[dp + i][cl];
            const unsigned short hh = f2bf(f);
            const unsigned short lo = f2bf(f - bf2f(hh));
            if (i < 8) { hv0[i] = (short)hh; lv0[i] = (short)lo; }
            else       { hv1[i - 8] = (short)hh; lv1[i - 8] = (short)lo; }
        }
        const size_t o = (size_t)(orow0 + cl) * D + dt * 64 + dp;
        *(bf16x8*)&dh[o] = hv0;
        *(bf16x8*)&dh[o + 8] = hv1;
        if (has_lo) {
            *(bf16x8*)&dl[o] = lv0;
            *(bf16x8*)&dl[o + 8] = lv1;
        }
    }
}

// ---------------------------------------------------------------------------
// K2: QKV projection (proven 161.5us config, R7-exact). grid (16, 48).
// Tile 128 rows x 64 cols, BK=64, DMA-staged. [0,16)=Q, [16,32)=K, [32,48)=V.
// Q scale folds 1/sqrt(64) AND log2(e): scores come out in log2 domain so
// attn softmax uses bare v_exp_f32 with no per-element multiply.
// V is written in the attn-LDS image layout (psi-permuted + XOR-swizzled,
// one 8192-short tile per (head, 128-row mtile)) so attn can dma16 it
// straight into LDS with perfectly coalesced reads.
// ---------------------------------------------------------------------------
__global__ __launch_bounds__(256, 3) void qkv_kernel(
    const unsigned short* __restrict__ xh, const unsigned short* __restrict__ xl,
    const unsigned short* __restrict__ wBh, const unsigned short* __restrict__ wBl,
    const unsigned short* __restrict__ wvt,
    unsigned short* __restrict__ Qh, unsigned short* __restrict__ Ql,
    unsigned short* __restrict__ Kh, unsigned short* __restrict__ Kl,
    unsigned short* __restrict__ Vt)
{
    __shared__ unsigned short ash[128 * 64], asl[128 * 64];
    __shared__ unsigned short bsh[64 * 64], bsl[64 * 64];
    const int n0 = blockIdx.x * 128;
    const int ct0 = blockIdx.y;
    const int sec = ct0 >> 4;            // 0=Q 1=K 2=V
    const int hh = ct0 & 15;
    const bool isv = (sec == 2);
    const unsigned short* Bh = isv ? wvt : wBh;
    const size_t brow0 = (sec == 1 ? 1024 : 0) + hh * 64;

    const int t = threadIdx.x;
    const int lane = t & 63, wvi = t >> 6, quad = lane >> 4, l15 = lane & 15;

    f32x4 acc[2][4];
    #pragma unroll
    for (int i = 0; i < 2; ++i)
        #pragma unroll
        for (int j = 0; j < 4; ++j) acc[i][j] = (f32x4){0.f, 0.f, 0.f, 0.f};

    for (int k0 = 0; k0 < D; k0 += 64) {
        __syncthreads();
        #pragma unroll
        for (int p = 0; p < 4; ++p) {
            const int row = p * 32 + wvi * 8 + (lane >> 3);
            const int lc = (lane & 7) ^ (row & 7);
            const int lo = p * 2048 + wvi * 512 + lane * 8;
            const size_t ga = (size_t)(n0 + row) * D + k0 + lc * 8;
            dma16(&xh[ga], &ash[lo]);
            if (!isv) dma16(&xl[ga], &asl[lo]);
        }
        #pragma unroll
        for (int p = 0; p < 2; ++p) {
            const int row = p * 32 + wvi * 8 + (lane >> 3);
            const int lc = (lane & 7) ^ (row & 7);
            const int lo = p * 2048 + wvi * 512 + lane * 8;
            const size_t gb = (brow0 + row) * D + k0 + lc * 8;
            dma16(&Bh[gb], &bsh[lo]);
            if (!isv) dma16(&wBl[gb], &bsl[lo]);
        }
        __syncthreads();

        #pragma unroll
        for (int kwi = 0; kwi < 2; ++kwi) {
            const int c = kwi * 4 + quad;
            bf16x8 ah[2], al[2], bh[4], bl[4];
            #pragma unroll
            for (int i = 0; i < 2; ++i) {
                ah[i] = *(const bf16x8*)&ash[sw8(wvi * 32 + i * 16 + l15, c)];
                if (!isv) al[i] = *(const bf16x8*)&asl[sw8(wvi * 32 + i * 16 + l15, c)];
            }
            #pragma unroll
            for (int j = 0; j < 4; ++j) {
                bh[j] = *(const bf16x8*)&bsh[sw8(j * 16 + l15, c)];
                if (!isv) bl[j] = *(const bf16x8*)&bsl[sw8(j * 16 + l15, c)];
            }
            #pragma unroll
            for (int i = 0; i < 2; ++i)
                #pragma unroll
                for (int j = 0; j < 4; ++j) {
                    acc[i][j] = MFMA(ah[i], bh[j], acc[i][j]);
                    if (!isv) {
                        acc[i][j] = MFMA(ah[i], bl[j], acc[i][j]);
                        acc[i][j] = MFMA(al[i], bh[j], acc[i][j]);
                    }
                }
        }
    }

    if (isv) {
        // thread holds V[n][e]: n = n0 + m, m = wvi*32 + i*16 + quad*4 + r,
        // e = j*16 + l15. vts-image position: chunk c16 = quad|(wvi<<2),
        // slot u = (i<<2)|r, off = e*128 + ((c16^(e&7))<<3) + u.
        const size_t tbase = ((size_t)hh * 16 + (n0 >> 7)) * 8192;
        const int c16 = quad | (wvi << 2);
        #pragma unroll
        for (int j = 0; j < 4; ++j) {
            const int e = j * 16 + l15;
            const int ebase = e * 128 + ((c16 ^ (e & 7)) << 3);
            #pragma unroll
            for (int i = 0; i < 2; ++i) {
                ushort4 pk;
                pk.x = f2bf(acc[i][j][0]);
                pk.y = f2bf(acc[i][j][1]);
                pk.z = f2bf(acc[i][j][2]);
                pk.w = f2bf(acc[i][j][3]);
                *(ushort4*)&Vt[tbase + ebase + (i << 2)] = pk;
            }
        }
    } else {
        // Q: 1/sqrt(64) * log2(e) = 0.125 * 1.4426950408889634
        const float scale = (sec == 0) ? 0.18033688011112042f : 1.0f;
        unsigned short* Oh = (sec == 0) ? Qh : Kh;
        unsigned short* Ol = (sec == 0) ? Ql : Kl;
        #pragma unroll
        for (int j = 0; j < 4; ++j) {
            const int e = j * 16 + l15;
            #pragma unroll
            for (int i = 0; i < 2; ++i)
                #pragma unroll
                for (int r = 0; r < 4; ++r) {
                    const int n = n0 + wvi * 32 + i * 16 + quad * 4 + r;
                    const float val = acc[i][j][r] * scale;
                    const unsigned short hv = f2bf(val);
                    Oh[((size_t)hh * N + n) * E + e] = hv;
                    Ol[((size_t)hh * N + n) * E + e] = f2bf(val - bf2f(hv));
                }
        }
    }
}

// ---------------------------------------------------------------------------
// K3: flash attention (proven KVBLK=128 config + setprio + exact defer-max +
// log2-domain softmax via bare v_exp_f32). Swapped-QK^T (S^T = K*Q^T) so
// softmax is lane-local; in-register P via cvt_pk. V arrives pre-permuted
// from qkv (global layout == LDS image) -> staged with 4 coalesced dma16.
// grid (16 q-tiles, 16 heads, 2 KV-splits); unnormalized O + (m,l) partials.
// ---------------------------------------------------------------------------
__global__ __launch_bounds__(256, 2) void attn_kernel(
    const unsigned short* __restrict__ Qh, const unsigned short* __restrict__ Ql,
    const unsigned short* __restrict__ Kh, const unsigned short* __restrict__ Kl,
    const unsigned short* __restrict__ Vt,
    unsigned short* __restrict__ Op0, unsigned short* __restrict__ Op1,
    float* __restrict__ mlp)
{
    __shared__ unsigned short kbuf[2 * 16384];   // [buf][ksh 8192 | ksl 8192] shorts
    __shared__ unsigned short vts[64 * 128];     // psi-permuted V tile [e][m-slot]
    const int r0 = blockIdx.x * 128, h = blockIdx.y, split = blockIdx.z;
    const int mb = split * 1024;
    const int t = threadIdx.x, lane = t & 63, wvi = t >> 6, quad = lane >> 4, l15 = lane & 15;

    // Q fragments: per-lane content works as MFMA B-operand (col=l15 -> q-row)
    bf16x8 qfh[2][2], qfl[2][2];
    #pragma unroll
    for (int i = 0; i < 2; ++i) {
        const size_t base = ((size_t)h * N + r0 + wvi * 32 + i * 16 + l15) * E;
        #pragma unroll
        for (int kwi = 0; kwi < 2; ++kwi) {
            qfh[i][kwi] = *(const bf16x8*)&Qh[base + kwi * 32 + quad * 8];
            qfl[i][kwi] = *(const bf16x8*)&Ql[base + kwi * 32 + quad * 8];
        }
    }

    // O^T accumulators: col=l15=q (group i), row=quad*4+r -> e=ct*16+quad*4+r
    f32x4 oacc[2][4];
    float mrow[2] = {-1e30f, -1e30f}, lrow[2] = {0.f, 0.f};
    #pragma unroll
    for (int i = 0; i < 2; ++i)
        #pragma unroll
        for (int j = 0; j < 4; ++j) oacc[i][j] = (f32x4){0.f, 0.f, 0.f, 0.f};

    // prologue: stage K tile 0 into buf 0
    #pragma unroll
    for (int p = 0; p < 4; ++p) {
        const int row = p * 32 + wvi * 8 + (lane >> 3);
        const int lc = (lane & 7) ^ (row & 7);
        const int lo = p * 2048 + wvi * 512 + lane * 8;
        const size_t gk = ((size_t)h * N + mb + row) * E + lc * 8;
        dma16(&Kh[gk], &kbuf[lo]);
        dma16(&Kl[gk], &kbuf[8192 + lo]);
    }

    for (int it = 0; it < 8; ++it) {
        const int cur = it & 1;
        // K[it] landed (vmcnt drain at barrier); vts free (PV of it-1 done)
        __syncthreads();

        // stage V[it] directly into vts: global layout == LDS image, so the
        // wave reads 1KB contiguous per issue (fully coalesced); lands at the
        // mid barrier, overlapping QK^T + softmax.
        {
            const size_t vtb = ((size_t)h * 16 + split * 8 + it) * 8192;
            const int lo = t * 8;
            #pragma unroll
            for (int q = 0; q < 4; ++q)
                dma16(&Vt[vtb + q * 2048 + lo], &vts[q * 2048 + lo]);
        }

        const unsigned short* ksh = &kbuf[cur * 16384];
        const unsigned short* ksl = ksh + 8192;

        // QK^T swapped: s[i][ct] = S^T (log2 domain), rows m=ct*16+quad*4+r
        f32x4 s[2][8];
        #pragma unroll
        for (int i = 0; i < 2; ++i)
            #pragma unroll
            for (int ct = 0; ct < 8; ++ct) s[i][ct] = (f32x4){0.f, 0.f, 0.f, 0.f};

        __builtin_amdgcn_s_setprio(1);
        #pragma unroll
        for (int kwi = 0; kwi < 2; ++kwi) {
            const int c = kwi * 4 + quad;
            #pragma unroll
            for (int ct = 0; ct < 8; ++ct) {
                const bf16x8 kh = *(const bf16x8*)&ksh[sw8(ct * 16 + l15, c)];
                const bf16x8 kl = *(const bf16x8*)&ksl[sw8(ct * 16 + l15, c)];
                #pragma unroll
                for (int i = 0; i < 2; ++i) {
                    s[i][ct] = MFMA(kh, qfh[i][kwi], s[i][ct]);
                    s[i][ct] = MFMA(kl, qfh[i][kwi], s[i][ct]);
                    s[i][ct] = MFMA(kh, qfl[i][kwi], s[i][ct]);
                }
            }
        }
        __builtin_amdgcn_s_setprio(0);

        // online softmax (log2 domain, bare v_exp_f32): lane owns q-row (i,l15)
        #pragma unroll
        for (int i = 0; i < 2; ++i) {
            float m0 = s[i][0][0], m1 = s[i][0][1], m2 = s[i][0][2], m3 = s[i][0][3];
            #pragma unroll
            for (int ct = 1; ct < 8; ++ct) {
                m0 = fmaxf(m0, s[i][ct][0]); m1 = fmaxf(m1, s[i][ct][1]);
                m2 = fmaxf(m2, s[i][ct][2]); m3 = fmaxf(m3, s[i][ct][3]);
            }
            float mx = fmaxf(fmaxf(m0, m1), fmaxf(m2, m3));
            mx = fmaxf(mx, __shfl_xor(mx, 16));
            mx = fmaxf(mx, __shfl_xor(mx, 32));
            // exact defer-max: alpha==1 when no lane's max grew -> skip rescale
            if (__any(mx > mrow[i])) {
                const float mn = fmaxf(mrow[i], mx);
                const float al = ex2(mrow[i] - mn);
                mrow[i] = mn;
                lrow[i] *= al;
                #pragma unroll
                for (int ct = 0; ct < 4; ++ct) {
                    oacc[i][ct][0] *= al; oacc[i][ct][1] *= al;
                    oacc[i][ct][2] *= al; oacc[i][ct][3] *= al;
                }
            }
            const float mn = mrow[i];
            float s0 = 0.f, s1 = 0.f, s2 = 0.f, s3 = 0.f;
            #pragma unroll
            for (int ct = 0; ct < 8; ++ct) {
                const float p0 = ex2(s[i][ct][0] - mn);
                const float p1 = ex2(s[i][ct][1] - mn);
                const float p2 = ex2(s[i][ct][2] - mn);
                const float p3 = ex2(s[i][ct][3] - mn);
                s[i][ct][0] = p0; s[i][ct][1] = p1;
                s[i][ct][2] = p2; s[i][ct][3] = p3;
                s0 += p0; s1 += p1; s2 += p2; s3 += p3;
            }
            float sum = (s0 + s1) + (s2 + s3);
            sum += __shfl_xor(sum, 16);
            sum += __shfl_xor(sum, 32);
            lrow[i] += sum;
        }

        // V[it] landed (vmcnt drain); all waves done reading kbuf[cur]
        __syncthreads();

        // prefetch K[it+1] (overlaps PV; drained at next top barrier)
        if (it < 7) {
            #pragma unroll
            for (int p = 0; p < 4; ++p) {
                const int row = p * 32 + wvi * 8 + (lane >> 3);
                const int lc = (lane & 7) ^ (row & 7);
                const int lo = (cur ^ 1) * 16384 + p * 2048 + wvi * 512 + lane * 8;
                const size_t gk = ((size_t)h * N + mb + it * 128 + 128 + row) * E + lc * 8;
                dma16(&Kh[gk], &kbuf[lo]);
                dma16(&Kl[gk], &kbuf[8192 + lo]);
            }
        }

        // PV: O^T += V^T(A) * P^T(B); B built in-register, zero LDS for P
        #pragma unroll
        for (int kb = 0; kb < 4; ++kb) {
            bf16x8 pb[2];
            #pragma unroll
            for (int i = 0; i < 2; ++i)
                pb[i] = pk4(cvtpk(s[i][2 * kb][0],     s[i][2 * kb][1]),
                            cvtpk(s[i][2 * kb][2],     s[i][2 * kb][3]),
                            cvtpk(s[i][2 * kb + 1][0], s[i][2 * kb + 1][1]),
                            cvtpk(s[i][2 * kb + 1][2], s[i][2 * kb + 1][3]));
            __builtin_amdgcn_s_setprio(1);
            #pragma unroll
            for (int ct = 0; ct < 4; ++ct) {
                const int re = ct * 16 + l15;
                const bf16x8 va =
                    *(const bf16x8*)&vts[re * 128 + (((kb * 4 + quad) ^ (re & 7)) << 3)];
                #pragma unroll
                for (int i = 0; i < 2; ++i)
                    oacc[i][ct] = MFMA(va, pb[i], oacc[i][ct]);
            }
            __builtin_amdgcn_s_setprio(0);
        }
    }

    // epilogue: unnormalized O (bf16) + (m,l) partials (m in log2 domain)
    unsigned short* Opc = split ? Op1 : Op0;
    #pragma unroll
    for (int i = 0; i < 2; ++i) {
        const int n = r0 + wvi * 32 + i * 16 + l15;
        if (quad == 0) {
            mlp[(((size_t)split * 16 + h) * 2048 + n) * 2 + 0] = mrow[i];
            mlp[(((size_t)split * 16 + h) * 2048 + n) * 2 + 1] = lrow[i];
        }
        #pragma unroll
        for (int ct = 0; ct < 4; ++ct) {
            ushort4 pk;
            pk.x = f2bf(oacc[i][ct][0]);
            pk.y = f2bf(oacc[i][ct][1]);
            pk.z = f2bf(oacc[i][ct][2]);
            pk.w = f2bf(oacc[i][ct][3]);
            *(ushort4*)&Opc[((size_t)h * 2048 + n) * 64 + ct * 16 + quad * 4] = pk;
        }
    }
}

// ---------------------------------------------------------------------------
// K3b: combine the two KV-split partials into Ch (log2-domain m). grid (32,16).
// ---------------------------------------------------------------------------
__global__ __launch_bounds__(256) void combine_kernel(
    const unsigned short* __restrict__ Op0, const unsigned short* __restrict__ Op1,
    const float* __restrict__ mlp, unsigned short* __restrict__ Ch)
{
    const int h = blockIdx.y;
    const int n = blockIdx.x * 64 + (threadIdx.x >> 2);
    const int e0 = (threadIdx.x & 3) * 16;
    const float m0 = mlp[((size_t)h * 2048 + n) * 2 + 0];
    const float l0 = mlp[((size_t)h * 2048 + n) * 2 + 1];
    const float m1 = mlp[((size_t)(16 + h) * 2048 + n) * 2 + 0];
    const float l1 = mlp[((size_t)(16 + h) * 2048 + n) * 2 + 1];
    const float M = fmaxf(m0, m1);
    const float a0 = ex2(m0 - M), a1 = ex2(m1 - M);
    const float inv = 1.f / (l0 * a0 + l1 * a1);
    const size_t ib = ((size_t)h * 2048 + n) * 64 + e0;
    const size_t ob = (size_t)n * D + h * 64 + e0;
    #pragma unroll
    for (int j = 0; j < 2; ++j) {
        const bf16x8 v0 = *(const bf16x8*)&Op0[ib + j * 8];
        const bf16x8 v1 = *(const bf16x8*)&Op1[ib + j * 8];
        bf16x8 o;
        #pragma unroll
        for (int k = 0; k < 8; ++k) {
            const float c = (bf2f((unsigned short)v0[k]) * a0 +
                             bf2f((unsigned short)v1[k]) * a1) * inv;
            o[k] = (short)f2bf(c);
        }
        *(bf16x8*)&Ch[ob + j * 8] = o;
    }
}

// ---------------------------------------------------------------------------
// K4: out = ctx @ Wo, single-term bf16. grid (32, 16); tile 64x64, BK=128
// (half the barrier drains of BK=64; LDS 32KB, still 4 blocks/CU).
// ---------------------------------------------------------------------------
__global__ __launch_bounds__(256, 4) void out_proj_kernel(
    const unsigned short* __restrict__ Chh, const unsigned short* __restrict__ Wh,
    float* __restrict__ out)
{
    __shared__ unsigned short ash[64 * 128], bsh[64 * 128];
    const int n0 = blockIdx.x * 64, c0 = blockIdx.y * 64;
    const int t = threadIdx.x, lane = t & 63, wvi = t >> 6, quad = lane >> 4, l15 = lane & 15;

    f32x4 acc[4];
    #pragma unroll
    for (int j = 0; j < 4; ++j) acc[j] = (f32x4){0.f, 0.f, 0.f, 0.f};

    for (int k0 = 0; k0 < D; k0 += 128) {
        __syncthreads();
        // stage 64x128 A and B tiles: thread covers row=p*16+wvi*4+quad,
        // chunk=l15 (16 chunks of 8 shorts per row), XOR-swizzled source col.
        #pragma unroll
        for (int p = 0; p < 4; ++p) {
            const int row = p * 16 + wvi * 4 + quad;
            const int lc = l15 ^ (row & 7);
            const int lo = p * 2048 + wvi * 512 + lane * 8;
            dma16(&Chh[(size_t)(n0 + row) * D + k0 + lc * 8], &ash[lo]);
            dma16(&Wh[(size_t)(c0 + row) * D + k0 + lc * 8], &bsh[lo]);
        }
        __syncthreads();

        #pragma unroll
        for (int kwi = 0; kwi < 4; ++kwi) {
            const int c = kwi * 4 + quad;
            const bf16x8 ah = *(const bf16x8*)&ash[sw16(wvi * 16 + l15, c)];
            #pragma unroll
            for (int j = 0; j < 4; ++j) {
                const bf16x8 bh = *(const bf16x8*)&bsh[sw16(j * 16 + l15, c)];
                acc[j] = MFMA(ah, bh, acc[j]);
            }
        }
    }

    #pragma unroll
    for (int r = 0; r < 4; ++r) {
        const int n = n0 + wvi * 16 + quad * 4 + r;
        #pragma unroll
        for (int j = 0; j < 4; ++j)
            out[(size_t)n * D + c0 + j * 16 + l15] = acc[j][r];
    }
}

// ---------------------------------------------------------------------------
extern "C" void kernel_launch(void* const* d_in, const int* in_sizes, int n_in,
                              void* d_out, int out_size, void* d_ws, size_t ws_size,
                              hipStream_t stream) {
    const float* x  = (const float*)d_in[0];
    const float* qw = (const float*)d_in[1];
    const float* kw = (const float*)d_in[2];
    const float* vw = (const float*)d_in[3];
    const float* ow = (const float*)d_in[4];
    float* out = (float*)d_out;

    unsigned short* ws = (unsigned short*)d_ws;
    const size_t M1 = 1024 * 1024;
    unsigned short* wBh = ws;                 // [2048][1024] = 2M shorts
    unsigned short* wBl = ws + 2 * M1;
    unsigned short* wvt = ws + 4 * M1;        // [1024][1024] = 1M
    unsigned short* woh = ws + 5 * M1;
    unsigned short* xh  = ws + 6 * M1;        // [2048][1024] = 2M
    unsigned short* xl  = ws + 8 * M1;
    unsigned short* Qh  = ws + 10 * M1;       // [h][n][e] = 2M each
    unsigned short* Ql  = ws + 12 * M1;
    unsigned short* Kh  = ws + 14 * M1;
    unsigned short* Kl  = ws + 16 * M1;
    unsigned short* Vt  = ws + 18 * M1;       // [h][mtile][8192] vts-image = 2M
    unsigned short* Ch  = xh;                 // alias: x dead after qkv

    // attn partials reuse regions dead after qkv:
    unsigned short* Op0 = wBh;                // [16][2048][64] bf16 = 2M shorts
    unsigned short* Op1 = wBl;                // [16][2048][64] bf16 = 2M shorts
    float* mlp = (float*)wvt;                 // [2][16][2048][2] f32 = 512KB

    convert_all_kernel<<<3072, 256, 0, stream>>>(x, qw, kw, vw, ow,
                                                 xh, xl, wBh, wBl, wvt, woh);
    qkv_kernel<<<dim3(16, 48), 256, 0, stream>>>(xh, xl, wBh, wBl, wvt,
                                                 Qh, Ql, Kh, Kl, Vt);
    attn_kernel<<<dim3(16, 16, 2), 256, 0, stream>>>(Qh, Ql, Kh, Kl, Vt,
                                                     Op0, Op1, mlp);
    combine_kernel<<<dim3(32, 16), 256, 0, stream>>>(Op0, Op1, mlp, Ch);
    out_proj_kernel<<<dim3(32, 16), 256, 0, stream>>>(Ch, woh, out);
}

// Round 13
// 162.834 us; speedup vs baseline: 1.0060x; 1.0060x over previous
//
#include <hip/hip_runtime.h>

#define H 16
#define N 2048
#define E 64
#define D 1024

typedef __attribute__((ext_vector_type(8))) short bf16x8;
typedef __attribute__((ext_vector_type(4))) float f32x4;
typedef __attribute__((ext_vector_type(4))) unsigned int u32x4;

__device__ __forceinline__ float bf2f(unsigned short u) {
    union { unsigned int i; float f; } v;
    v.i = ((unsigned int)u) << 16;
    return v.f;
}
__device__ __forceinline__ unsigned short f2bf(float f) {
    unsigned int u = __float_as_uint(f);
    return (unsigned short)((u + 0x7fffu + ((u >> 16) & 1u)) >> 16);
}
// v_cvt_pk_bf16_f32: D.lo = bf16(lo), D.hi = bf16(hi)
__device__ __forceinline__ unsigned int cvtpk(float lo, float hi) {
    unsigned int r;
    asm("v_cvt_pk_bf16_f32 %0, %1, %2" : "=v"(r) : "v"(lo), "v"(hi));
    return r;
}
__device__ __forceinline__ bf16x8 pk4(unsigned int a, unsigned int b,
                                      unsigned int c, unsigned int d) {
    union { u32x4 u; bf16x8 h; } x;
    x.u = (u32x4){a, b, c, d};
    return x.h;
}
// bare hardware exp2: v_exp_f32 computes D = 2^S0 (one transcendental op;
// exp2f() would lower to the precise OCML routine, ~6 ops -- measured R6)
__device__ __forceinline__ float ex2(float x) {
    float r;
    asm("v_exp_f32 %0, %1" : "=v"(r) : "v"(x));
    return r;
}
#define MFMA(a, b, c) __builtin_amdgcn_mfma_f32_16x16x32_bf16(a, b, c, 0, 0, 0)

// async global->LDS, 16B per lane. LDS dest must be base+lane*16 contiguous.
typedef __attribute__((address_space(3))) unsigned int lds_u32;
typedef const __attribute__((address_space(1))) unsigned int glb_u32;
__device__ __forceinline__ void dma16(const unsigned short* g, unsigned short* l) {
    __builtin_amdgcn_global_load_lds((glb_u32*)g, (lds_u32*)l, 16, 0, 0);
}

// XOR-swizzled LDS tiles (16B chunk granularity): physical chunk = c ^ (row&7).
__device__ __forceinline__ int sw8(int row, int c)  { return row * 64  + ((c ^ (row & 7)) << 3); }
__device__ __forceinline__ int sw16(int row, int c) { return row * 128 + ((c ^ (row & 7)) << 3); }

// ---------------------------------------------------------------------------
// K1: merged converts. blocks [0,2048): x fp32 -> xh/xl.
// blocks [2048,3072): weights. q -> wBh/wBl rows [0,1024); k -> rows
// [1024,2048); v -> wvt [h*64+e][d] (hi only); o -> woh [c][d] (hi only).
// ---------------------------------------------------------------------------
__global__ __launch_bounds__(256) void convert_all_kernel(
    const float* __restrict__ x,
    const float* __restrict__ qw, const float* __restrict__ kw,
    const float* __restrict__ vw, const float* __restrict__ ow,
    unsigned short* __restrict__ xh, unsigned short* __restrict__ xl,
    unsigned short* __restrict__ wBh, unsigned short* __restrict__ wBl,
    unsigned short* __restrict__ wvt, unsigned short* __restrict__ woh)
{
    __shared__ float ts[64][65];
    const int b0 = blockIdx.x;
    const int t = threadIdx.x;
    if (b0 < 2048) {
        const int i = (b0 * 256 + t) * 4;
        const float4 v = *(const float4*)&x[i];
        ushort4 hh, ll;
        hh.x = f2bf(v.x); ll.x = f2bf(v.x - bf2f(hh.x));
        hh.y = f2bf(v.y); ll.y = f2bf(v.y - bf2f(hh.y));
        hh.z = f2bf(v.z); ll.z = f2bf(v.z - bf2f(hh.z));
        hh.w = f2bf(v.w); ll.w = f2bf(v.w - bf2f(hh.w));
        *(ushort4*)&xh[i] = hh;
        *(ushort4*)&xl[i] = ll;
        return;
    }
    const int b = b0 - 2048;
    const float* src;
    int rs, dt, orow0;
    bool has_lo;
    unsigned short *dh, *dl;
    if (b < 768) {
        const int which = b >> 8, r = b & 255, h = r >> 4;
        dt = r & 15;
        src = (which == 0 ? qw : which == 1 ? kw : vw) + ((size_t)h * D + dt * 64) * E;
        rs = E;
        if (which == 0)      { dh = wBh; dl = wBl; orow0 = h * 64;        has_lo = true; }
        else if (which == 1) { dh = wBh; dl = wBl; orow0 = 1024 + h * 64; has_lo = true; }
        else                 { dh = wvt; dl = wBl; orow0 = h * 64;        has_lo = false; }
    } else {
        const int r = b - 768, ct = r >> 4;
        dt = r & 15;
        src = ow + (size_t)(dt * 64) * D + ct * 64;
        rs = D;
        orow0 = ct * 64;
        dh = woh; dl = wBl; has_lo = false;   // o: hi only
    }
    {
        const int row = t >> 2, cb = (t & 3) * 16;
        #pragma unroll
        for (int j = 0; j < 16; j += 4) {
            const float4 v = *(const float4*)&src[row * rs + cb + j];
            ts[row][cb + j + 0] = v.x;
            ts[row][cb + j + 1] = v.y;
            ts[row][cb + j + 2] = v.z;
            ts[row][cb + j + 3] = v.w;
        }
    }
    __syncthreads();
    {
        const int cl = t >> 2, dp = (t & 3) * 16;
        bf16x8 hv0, hv1, lv0, lv1;
        #pragma unroll
        for (int i = 0; i < 16; ++i) {
            const float f = ts[dp + i][cl];
            const unsigned short hh = f2bf(f);
            const unsigned short lo = f2bf(f - bf2f(hh));
            if (i < 8) { hv0[i] = (short)hh; lv0[i] = (short)lo; }
            else       { hv1[i - 8] = (short)hh; lv1[i - 8] = (short)lo; }
        }
        const size_t o = (size_t)(orow0 + cl) * D + dt * 64 + dp;
        *(bf16x8*)&dh[o] = hv0;
        *(bf16x8*)&dh[o + 8] = hv1;
        if (has_lo) {
            *(bf16x8*)&dl[o] = lv0;
            *(bf16x8*)&dl[o + 8] = lv1;
        }
    }
}

// ---------------------------------------------------------------------------
// K2: QKV projection (proven 161.5us config, R7-exact). grid (16, 48).
// Tile 128 rows x 64 cols, BK=64, DMA-staged. [0,16)=Q, [16,32)=K, [32,48)=V.
// Q scale folds 1/sqrt(64) AND log2(e): scores come out in log2 domain so
// attn softmax uses bare v_exp_f32 with no per-element multiply.
// ---------------------------------------------------------------------------
__global__ __launch_bounds__(256, 3) void qkv_kernel(
    const unsigned short* __restrict__ xh, const unsigned short* __restrict__ xl,
    const unsigned short* __restrict__ wBh, const unsigned short* __restrict__ wBl,
    const unsigned short* __restrict__ wvt,
    unsigned short* __restrict__ Qh, unsigned short* __restrict__ Ql,
    unsigned short* __restrict__ Kh, unsigned short* __restrict__ Kl,
    unsigned short* __restrict__ Vt)
{
    __shared__ unsigned short ash[128 * 64], asl[128 * 64];
    __shared__ unsigned short bsh[64 * 64], bsl[64 * 64];
    const int n0 = blockIdx.x * 128;
    const int ct0 = blockIdx.y;
    const int sec = ct0 >> 4;            // 0=Q 1=K 2=V
    const int hh = ct0 & 15;
    const bool isv = (sec == 2);
    const unsigned short* Bh = isv ? wvt : wBh;
    const size_t brow0 = (sec == 1 ? 1024 : 0) + hh * 64;

    const int t = threadIdx.x;
    const int lane = t & 63, wvi = t >> 6, quad = lane >> 4, l15 = lane & 15;

    f32x4 acc[2][4];
    #pragma unroll
    for (int i = 0; i < 2; ++i)
        #pragma unroll
        for (int j = 0; j < 4; ++j) acc[i][j] = (f32x4){0.f, 0.f, 0.f, 0.f};

    for (int k0 = 0; k0 < D; k0 += 64) {
        __syncthreads();
        #pragma unroll
        for (int p = 0; p < 4; ++p) {
            const int row = p * 32 + wvi * 8 + (lane >> 3);
            const int lc = (lane & 7) ^ (row & 7);
            const int lo = p * 2048 + wvi * 512 + lane * 8;
            const size_t ga = (size_t)(n0 + row) * D + k0 + lc * 8;
            dma16(&xh[ga], &ash[lo]);
            if (!isv) dma16(&xl[ga], &asl[lo]);
        }
        #pragma unroll
        for (int p = 0; p < 2; ++p) {
            const int row = p * 32 + wvi * 8 + (lane >> 3);
            const int lc = (lane & 7) ^ (row & 7);
            const int lo = p * 2048 + wvi * 512 + lane * 8;
            const size_t gb = (brow0 + row) * D + k0 + lc * 8;
            dma16(&Bh[gb], &bsh[lo]);
            if (!isv) dma16(&wBl[gb], &bsl[lo]);
        }
        __syncthreads();

        #pragma unroll
        for (int kwi = 0; kwi < 2; ++kwi) {
            const int c = kwi * 4 + quad;
            bf16x8 ah[2], al[2], bh[4], bl[4];
            #pragma unroll
            for (int i = 0; i < 2; ++i) {
                ah[i] = *(const bf16x8*)&ash[sw8(wvi * 32 + i * 16 + l15, c)];
                if (!isv) al[i] = *(const bf16x8*)&asl[sw8(wvi * 32 + i * 16 + l15, c)];
            }
            #pragma unroll
            for (int j = 0; j < 4; ++j) {
                bh[j] = *(const bf16x8*)&bsh[sw8(j * 16 + l15, c)];
                if (!isv) bl[j] = *(const bf16x8*)&bsl[sw8(j * 16 + l15, c)];
            }
            #pragma unroll
            for (int i = 0; i < 2; ++i)
                #pragma unroll
                for (int j = 0; j < 4; ++j) {
                    acc[i][j] = MFMA(ah[i], bh[j], acc[i][j]);
                    if (!isv) {
                        acc[i][j] = MFMA(ah[i], bl[j], acc[i][j]);
                        acc[i][j] = MFMA(al[i], bh[j], acc[i][j]);
                    }
                }
        }
    }

    if (isv) {
        #pragma unroll
        for (int j = 0; j < 4; ++j) {
            const int e = j * 16 + l15;
            #pragma unroll
            for (int i = 0; i < 2; ++i) {
                const int nb = n0 + wvi * 32 + i * 16 + quad * 4;
                ushort4 pk;
                pk.x = f2bf(acc[i][j][0]);
                pk.y = f2bf(acc[i][j][1]);
                pk.z = f2bf(acc[i][j][2]);
                pk.w = f2bf(acc[i][j][3]);
                *(ushort4*)&Vt[((size_t)hh * 64 + e) * N + nb] = pk;
            }
        }
    } else {
        // Q: 1/sqrt(64) * log2(e) = 0.125 * 1.4426950408889634
        const float scale = (sec == 0) ? 0.18033688011112042f : 1.0f;
        unsigned short* Oh = (sec == 0) ? Qh : Kh;
        unsigned short* Ol = (sec == 0) ? Ql : Kl;
        #pragma unroll
        for (int j = 0; j < 4; ++j) {
            const int e = j * 16 + l15;
            #pragma unroll
            for (int i = 0; i < 2; ++i)
                #pragma unroll
                for (int r = 0; r < 4; ++r) {
                    const int n = n0 + wvi * 32 + i * 16 + quad * 4 + r;
                    const float val = acc[i][j][r] * scale;
                    const unsigned short hv = f2bf(val);
                    Oh[((size_t)hh * N + n) * E + e] = hv;
                    Ol[((size_t)hh * N + n) * E + e] = f2bf(val - bf2f(hv));
                }
        }
    }
}

// ---------------------------------------------------------------------------
// K3: flash attention (proven KVBLK=128 config + setprio + exact defer-max +
// log2-domain softmax via bare v_exp_f32). Swapped-QK^T (S^T = K*Q^T) so
// softmax is lane-local; in-register P via cvt_pk; psi-permuted reg-staged V.
// grid (16 q-tiles, 16 heads, 2 KV-splits); unnormalized O + (m,l) partials.
// ---------------------------------------------------------------------------
__global__ __launch_bounds__(256, 2) void attn_kernel(
    const unsigned short* __restrict__ Qh, const unsigned short* __restrict__ Ql,
    const unsigned short* __restrict__ Kh, const unsigned short* __restrict__ Kl,
    const unsigned short* __restrict__ Vt,
    unsigned short* __restrict__ Op0, unsigned short* __restrict__ Op1,
    float* __restrict__ mlp)
{
    __shared__ unsigned short kbuf[2 * 16384];   // [buf][ksh 8192 | ksl 8192] shorts
    __shared__ unsigned short vts[64 * 128];     // psi-permuted V tile [e][m-slot]
    const int r0 = blockIdx.x * 128, h = blockIdx.y, split = blockIdx.z;
    const int mb = split * 1024;
    const int t = threadIdx.x, lane = t & 63, wvi = t >> 6, quad = lane >> 4, l15 = lane & 15;

    // Q fragments: per-lane content works as MFMA B-operand (col=l15 -> q-row)
    bf16x8 qfh[2][2], qfl[2][2];
    #pragma unroll
    for (int i = 0; i < 2; ++i) {
        const size_t base = ((size_t)h * N + r0 + wvi * 32 + i * 16 + l15) * E;
        #pragma unroll
        for (int kwi = 0; kwi < 2; ++kwi) {
            qfh[i][kwi] = *(const bf16x8*)&Qh[base + kwi * 32 + quad * 8];
            qfl[i][kwi] = *(const bf16x8*)&Ql[base + kwi * 32 + quad * 8];
        }
    }

    // O^T accumulators: col=l15=q (group i), row=quad*4+r -> e=ct*16+quad*4+r
    f32x4 oacc[2][4];
    float mrow[2] = {-1e30f, -1e30f}, lrow[2] = {0.f, 0.f};
    #pragma unroll
    for (int i = 0; i < 2; ++i)
        #pragma unroll
        for (int j = 0; j < 4; ++j) oacc[i][j] = (f32x4){0.f, 0.f, 0.f, 0.f};

    // V staging map: thread covers e = wvi*16 + (lane>>2), c16 = (lane&3)*4 + z
    const int ve = wvi * 16 + (lane >> 2);
    const int vc = lane & 3;

    // prologue: stage K tile 0 into buf 0
    #pragma unroll
    for (int p = 0; p < 4; ++p) {
        const int row = p * 32 + wvi * 8 + (lane >> 3);
        const int lc = (lane & 7) ^ (row & 7);
        const int lo = p * 2048 + wvi * 512 + lane * 8;
        const size_t gk = ((size_t)h * N + mb + row) * E + lc * 8;
        dma16(&Kh[gk], &kbuf[lo]);
        dma16(&Kl[gk], &kbuf[8192 + lo]);
    }

    for (int it = 0; it < 8; ++it) {
        const int cur = it & 1;
        // K[it] landed (vmcnt drain at barrier); vts free (PV of it-1 done)
        __syncthreads();
        const int mcol = mb + it * 128;

        // V -> regs early (psi-permuted 8B pairs); consumed at vts write below
        uint2 vr0[4], vr1[4];
        #pragma unroll
        for (int z = 0; z < 4; ++z) {
            const size_t gb = ((size_t)h * 64 + ve) * N + mcol + vc * 32 + z * 4;
            vr0[z] = *(const uint2*)&Vt[gb];
            vr1[z] = *(const uint2*)&Vt[gb + 16];
        }

        const unsigned short* ksh = &kbuf[cur * 16384];
        const unsigned short* ksl = ksh + 8192;

        // QK^T swapped: s[i][ct] = S^T (log2 domain), rows m=ct*16+quad*4+r
        f32x4 s[2][8];
        #pragma unroll
        for (int i = 0; i < 2; ++i)
            #pragma unroll
            for (int ct = 0; ct < 8; ++ct) s[i][ct] = (f32x4){0.f, 0.f, 0.f, 0.f};

        __builtin_amdgcn_s_setprio(1);
        #pragma unroll
        for (int kwi = 0; kwi < 2; ++kwi) {
            const int c = kwi * 4 + quad;
            #pragma unroll
            for (int ct = 0; ct < 8; ++ct) {
                const bf16x8 kh = *(const bf16x8*)&ksh[sw8(ct * 16 + l15, c)];
                const bf16x8 kl = *(const bf16x8*)&ksl[sw8(ct * 16 + l15, c)];
                #pragma unroll
                for (int i = 0; i < 2; ++i) {
                    s[i][ct] = MFMA(kh, qfh[i][kwi], s[i][ct]);
                    s[i][ct] = MFMA(kl, qfh[i][kwi], s[i][ct]);
                    s[i][ct] = MFMA(kh, qfl[i][kwi], s[i][ct]);
                }
            }
        }
        __builtin_amdgcn_s_setprio(0);

        // online softmax (log2 domain, bare v_exp_f32): lane owns q-row (i,l15)
        #pragma unroll
        for (int i = 0; i < 2; ++i) {
            float m0 = s[i][0][0], m1 = s[i][0][1], m2 = s[i][0][2], m3 = s[i][0][3];
            #pragma unroll
            for (int ct = 1; ct < 8; ++ct) {
                m0 = fmaxf(m0, s[i][ct][0]); m1 = fmaxf(m1, s[i][ct][1]);
                m2 = fmaxf(m2, s[i][ct][2]); m3 = fmaxf(m3, s[i][ct][3]);
            }
            float mx = fmaxf(fmaxf(m0, m1), fmaxf(m2, m3));
            mx = fmaxf(mx, __shfl_xor(mx, 16));
            mx = fmaxf(mx, __shfl_xor(mx, 32));
            // exact defer-max: alpha==1 when no lane's max grew -> skip rescale
            if (__any(mx > mrow[i])) {
                const float mn = fmaxf(mrow[i], mx);
                const float al = ex2(mrow[i] - mn);
                mrow[i] = mn;
                lrow[i] *= al;
                #pragma unroll
                for (int ct = 0; ct < 4; ++ct) {
                    oacc[i][ct][0] *= al; oacc[i][ct][1] *= al;
                    oacc[i][ct][2] *= al; oacc[i][ct][3] *= al;
                }
            }
            const float mn = mrow[i];
            float s0 = 0.f, s1 = 0.f, s2 = 0.f, s3 = 0.f;
            #pragma unroll
            for (int ct = 0; ct < 8; ++ct) {
                const float p0 = ex2(s[i][ct][0] - mn);
                const float p1 = ex2(s[i][ct][1] - mn);
                const float p2 = ex2(s[i][ct][2] - mn);
                const float p3 = ex2(s[i][ct][3] - mn);
                s[i][ct][0] = p0; s[i][ct][1] = p1;
                s[i][ct][2] = p2; s[i][ct][3] = p3;
                s0 += p0; s1 += p1; s2 += p2; s3 += p3;
            }
            float sum = (s0 + s1) + (s2 + s3);
            sum += __shfl_xor(sum, 16);
            sum += __shfl_xor(sum, 32);
            lrow[i] += sum;
        }

        // write V tile: phys chunk c16 ^ (e&7); slots p=c16*8+u hold
        // V[m0 + (c16>>2)*32 + (u>>2)*16 + (c16&3)*4 + (u&3)][e]
        #pragma unroll
        for (int z = 0; z < 4; ++z) {
            const int c16 = vc * 4 + z;
            u32x4 w = (u32x4){vr0[z].x, vr0[z].y, vr1[z].x, vr1[z].y};
            *(u32x4*)&vts[ve * 128 + ((c16 ^ (ve & 7)) << 3)] = w;
        }
        __syncthreads();

        // prefetch K[it+1] (overlaps PV; drained at next top barrier)
        if (it < 7) {
            #pragma unroll
            for (int p = 0; p < 4; ++p) {
                const int row = p * 32 + wvi * 8 + (lane >> 3);
                const int lc = (lane & 7) ^ (row & 7);
                const int lo = (cur ^ 1) * 16384 + p * 2048 + wvi * 512 + lane * 8;
                const size_t gk = ((size_t)h * N + mcol + 128 + row) * E + lc * 8;
                dma16(&Kh[gk], &kbuf[lo]);
                dma16(&Kl[gk], &kbuf[8192 + lo]);
            }
        }

        // PV: O^T += V^T(A) * P^T(B); B built in-register, zero LDS for P
        #pragma unroll
        for (int kb = 0; kb < 4; ++kb) {
            bf16x8 pb[2];
            #pragma unroll
            for (int i = 0; i < 2; ++i)
                pb[i] = pk4(cvtpk(s[i][2 * kb][0],     s[i][2 * kb][1]),
                            cvtpk(s[i][2 * kb][2],     s[i][2 * kb][3]),
                            cvtpk(s[i][2 * kb + 1][0], s[i][2 * kb + 1][1]),
                            cvtpk(s[i][2 * kb + 1][2], s[i][2 * kb + 1][3]));
            __builtin_amdgcn_s_setprio(1);
            #pragma unroll
            for (int ct = 0; ct < 4; ++ct) {
                const int re = ct * 16 + l15;
                const bf16x8 va =
                    *(const bf16x8*)&vts[re * 128 + (((kb * 4 + quad) ^ (re & 7)) << 3)];
                #pragma unroll
                for (int i = 0; i < 2; ++i)
                    oacc[i][ct] = MFMA(va, pb[i], oacc[i][ct]);
            }
            __builtin_amdgcn_s_setprio(0);
        }
    }

    // epilogue: unnormalized O (bf16) + (m,l) partials (m in log2 domain)
    unsigned short* Opc = split ? Op1 : Op0;
    #pragma unroll
    for (int i = 0; i < 2; ++i) {
        const int n = r0 + wvi * 32 + i * 16 + l15;
        if (quad == 0) {
            mlp[(((size_t)split * 16 + h) * 2048 + n) * 2 + 0] = mrow[i];
            mlp[(((size_t)split * 16 + h) * 2048 + n) * 2 + 1] = lrow[i];
        }
        #pragma unroll
        for (int ct = 0; ct < 4; ++ct) {
            ushort4 pk;
            pk.x = f2bf(oacc[i][ct][0]);
            pk.y = f2bf(oacc[i][ct][1]);
            pk.z = f2bf(oacc[i][ct][2]);
            pk.w = f2bf(oacc[i][ct][3]);
            *(ushort4*)&Opc[((size_t)h * 2048 + n) * 64 + ct * 16 + quad * 4] = pk;
        }
    }
}

// ---------------------------------------------------------------------------
// K3b: combine the two KV-split partials into Ch (log2-domain m). grid (32,16).
// ---------------------------------------------------------------------------
__global__ __launch_bounds__(256) void combine_kernel(
    const unsigned short* __restrict__ Op0, const unsigned short* __restrict__ Op1,
    const float* __restrict__ mlp, unsigned short* __restrict__ Ch)
{
    const int h = blockIdx.y;
    const int n = blockIdx.x * 64 + (threadIdx.x >> 2);
    const int e0 = (threadIdx.x & 3) * 16;
    const float m0 = mlp[((size_t)h * 2048 + n) * 2 + 0];
    const float l0 = mlp[((size_t)h * 2048 + n) * 2 + 1];
    const float m1 = mlp[((size_t)(16 + h) * 2048 + n) * 2 + 0];
    const float l1 = mlp[((size_t)(16 + h) * 2048 + n) * 2 + 1];
    const float M = fmaxf(m0, m1);
    const float a0 = ex2(m0 - M), a1 = ex2(m1 - M);
    const float inv = 1.f / (l0 * a0 + l1 * a1);
    const size_t ib = ((size_t)h * 2048 + n) * 64 + e0;
    const size_t ob = (size_t)n * D + h * 64 + e0;
    #pragma unroll
    for (int j = 0; j < 2; ++j) {
        const bf16x8 v0 = *(const bf16x8*)&Op0[ib + j * 8];
        const bf16x8 v1 = *(const bf16x8*)&Op1[ib + j * 8];
        bf16x8 o;
        #pragma unroll
        for (int k = 0; k < 8; ++k) {
            const float c = (bf2f((unsigned short)v0[k]) * a0 +
                             bf2f((unsigned short)v1[k]) * a1) * inv;
            o[k] = (short)f2bf(c);
        }
        *(bf16x8*)&Ch[ob + j * 8] = o;
    }
}

// ---------------------------------------------------------------------------
// K4: out = ctx @ Wo, single-term bf16. grid (32, 16); tile 64x64, BK=128
// (half the barrier drains of BK=64; LDS 32KB, still 4 blocks/CU).
// ---------------------------------------------------------------------------
__global__ __launch_bounds__(256, 4) void out_proj_kernel(
    const unsigned short* __restrict__ Chh, const unsigned short* __restrict__ Wh,
    float* __restrict__ out)
{
    __shared__ unsigned short ash[64 * 128], bsh[64 * 128];
    const int n0 = blockIdx.x * 64, c0 = blockIdx.y * 64;
    const int t = threadIdx.x, lane = t & 63, wvi = t >> 6, quad = lane >> 4, l15 = lane & 15;

    f32x4 acc[4];
    #pragma unroll
    for (int j = 0; j < 4; ++j) acc[j] = (f32x4){0.f, 0.f, 0.f, 0.f};

    for (int k0 = 0; k0 < D; k0 += 128) {
        __syncthreads();
        // stage 64x128 A and B tiles: thread covers row=p*16+wvi*4+quad,
        // chunk=l15 (16 chunks of 8 shorts per row), XOR-swizzled source col.
        #pragma unroll
        for (int p = 0; p < 4; ++p) {
            const int row = p * 16 + wvi * 4 + quad;
            const int lc = l15 ^ (row & 7);
            const int lo = p * 2048 + wvi * 512 + lane * 8;
            dma16(&Chh[(size_t)(n0 + row) * D + k0 + lc * 8], &ash[lo]);
            dma16(&Wh[(size_t)(c0 + row) * D + k0 + lc * 8], &bsh[lo]);
        }
        __syncthreads();

        #pragma unroll
        for (int kwi = 0; kwi < 4; ++kwi) {
            const int c = kwi * 4 + quad;
            const bf16x8 ah = *(const bf16x8*)&ash[sw16(wvi * 16 + l15, c)];
            #pragma unroll
            for (int j = 0; j < 4; ++j) {
                const bf16x8 bh = *(const bf16x8*)&bsh[sw16(j * 16 + l15, c)];
                acc[j] = MFMA(ah, bh, acc[j]);
            }
        }
    }

    #pragma unroll
    for (int r = 0; r < 4; ++r) {
        const int n = n0 + wvi * 16 + quad * 4 + r;
        #pragma unroll
        for (int j = 0; j < 4; ++j)
            out[(size_t)n * D + c0 + j * 16 + l15] = acc[j][r];
    }
}

// ---------------------------------------------------------------------------
extern "C" void kernel_launch(void* const* d_in, const int* in_sizes, int n_in,
                              void* d_out, int out_size, void* d_ws, size_t ws_size,
                              hipStream_t stream) {
    const float* x  = (const float*)d_in[0];
    const float* qw = (const float*)d_in[1];
    const float* kw = (const float*)d_in[2];
    const float* vw = (const float*)d_in[3];
    const float* ow = (const float*)d_in[4];
    float* out = (float*)d_out;

    unsigned short* ws = (unsigned short*)d_ws;
    const size_t M1 = 1024 * 1024;
    unsigned short* wBh = ws;                 // [2048][1024] = 2M shorts
    unsigned short* wBl = ws + 2 * M1;
    unsigned short* wvt = ws + 4 * M1;        // [1024][1024] = 1M
    unsigned short* woh = ws + 5 * M1;
    unsigned short* xh  = ws + 6 * M1;        // [2048][1024] = 2M
    unsigned short* xl  = ws + 8 * M1;
    unsigned short* Qh  = ws + 10 * M1;       // [h][n][e] = 2M each
    unsigned short* Ql  = ws + 12 * M1;
    unsigned short* Kh  = ws + 14 * M1;
    unsigned short* Kl  = ws + 16 * M1;
    unsigned short* Vt  = ws + 18 * M1;       // [h*64+e][n] = 2M
    unsigned short* Ch  = xh;                 // alias: x dead after qkv

    // attn partials reuse regions dead after qkv:
    unsigned short* Op0 = wBh;                // [16][2048][64] bf16 = 2M shorts
    unsigned short* Op1 = wBl;                // [16][2048][64] bf16 = 2M shorts
    float* mlp = (float*)wvt;                 // [2][16][2048][2] f32 = 512KB

    convert_all_kernel<<<3072, 256, 0, stream>>>(x, qw, kw, vw, ow,
                                                 xh, xl, wBh, wBl, wvt, woh);
    qkv_kernel<<<dim3(16, 48), 256, 0, stream>>>(xh, xl, wBh, wBl, wvt,
                                                 Qh, Ql, Kh, Kl, Vt);
    attn_kernel<<<dim3(16, 16, 2), 256, 0, stream>>>(Qh, Ql, Kh, Kl, Vt,
                                                     Op0, Op1, mlp);
    combine_kernel<<<dim3(32, 16), 256, 0, stream>>>(Op0, Op1, mlp, Ch);
    out_proj_kernel<<<dim3(32, 16), 256, 0, stream>>>(Ch, woh, out);
}

// Round 14
// 161.425 us; speedup vs baseline: 1.0148x; 1.0087x over previous
//
#include <hip/hip_runtime.h>

#define H 16
#define N 2048
#define E 64
#define D 1024

typedef __attribute__((ext_vector_type(8))) short bf16x8;
typedef __attribute__((ext_vector_type(4))) float f32x4;
typedef __attribute__((ext_vector_type(4))) unsigned int u32x4;

__device__ __forceinline__ float bf2f(unsigned short u) {
    union { unsigned int i; float f; } v;
    v.i = ((unsigned int)u) << 16;
    return v.f;
}
__device__ __forceinline__ unsigned short f2bf(float f) {
    unsigned int u = __float_as_uint(f);
    return (unsigned short)((u + 0x7fffu + ((u >> 16) & 1u)) >> 16);
}
// v_cvt_pk_bf16_f32: D.lo = bf16(lo), D.hi = bf16(hi)
__device__ __forceinline__ unsigned int cvtpk(float lo, float hi) {
    unsigned int r;
    asm("v_cvt_pk_bf16_f32 %0, %1, %2" : "=v"(r) : "v"(lo), "v"(hi));
    return r;
}
__device__ __forceinline__ bf16x8 pk4(unsigned int a, unsigned int b,
                                      unsigned int c, unsigned int d) {
    union { u32x4 u; bf16x8 h; } x;
    x.u = (u32x4){a, b, c, d};
    return x.h;
}
// bare hardware exp2: v_exp_f32 computes D = 2^S0 (one transcendental op;
// exp2f() would lower to the precise OCML routine, ~6 ops -- measured R6)
__device__ __forceinline__ float ex2(float x) {
    float r;
    asm("v_exp_f32 %0, %1" : "=v"(r) : "v"(x));
    return r;
}
#define MFMA(a, b, c) __builtin_amdgcn_mfma_f32_16x16x32_bf16(a, b, c, 0, 0, 0)

// async global->LDS, 16B per lane. LDS dest must be base+lane*16 contiguous.
typedef __attribute__((address_space(3))) unsigned int lds_u32;
typedef const __attribute__((address_space(1))) unsigned int glb_u32;
__device__ __forceinline__ void dma16(const unsigned short* g, unsigned short* l) {
    __builtin_amdgcn_global_load_lds((glb_u32*)g, (lds_u32*)l, 16, 0, 0);
}

// XOR-swizzled LDS tiles (16B chunk granularity): physical chunk = c ^ (row&7).
__device__ __forceinline__ int sw8(int row, int c)  { return row * 64  + ((c ^ (row & 7)) << 3); }
__device__ __forceinline__ int sw16(int row, int c) { return row * 128 + ((c ^ (row & 7)) << 3); }

// ---------------------------------------------------------------------------
// K1: merged converts. blocks [0,2048): x fp32 -> xh/xl.
// blocks [2048,3072): weights. q -> wBh/wBl rows [0,1024); k -> rows
// [1024,2048); v -> wvt [h*64+e][d] (hi only); o -> woh [c][d] (hi only).
// ---------------------------------------------------------------------------
__global__ __launch_bounds__(256) void convert_all_kernel(
    const float* __restrict__ x,
    const float* __restrict__ qw, const float* __restrict__ kw,
    const float* __restrict__ vw, const float* __restrict__ ow,
    unsigned short* __restrict__ xh, unsigned short* __restrict__ xl,
    unsigned short* __restrict__ wBh, unsigned short* __restrict__ wBl,
    unsigned short* __restrict__ wvt, unsigned short* __restrict__ woh)
{
    __shared__ float ts[64][65];
    const int b0 = blockIdx.x;
    const int t = threadIdx.x;
    if (b0 < 2048) {
        const int i = (b0 * 256 + t) * 4;
        const float4 v = *(const float4*)&x[i];
        ushort4 hh, ll;
        hh.x = f2bf(v.x); ll.x = f2bf(v.x - bf2f(hh.x));
        hh.y = f2bf(v.y); ll.y = f2bf(v.y - bf2f(hh.y));
        hh.z = f2bf(v.z); ll.z = f2bf(v.z - bf2f(hh.z));
        hh.w = f2bf(v.w); ll.w = f2bf(v.w - bf2f(hh.w));
        *(ushort4*)&xh[i] = hh;
        *(ushort4*)&xl[i] = ll;
        return;
    }
    const int b = b0 - 2048;
    const float* src;
    int rs, dt, orow0;
    bool has_lo;
    unsigned short *dh, *dl;
    if (b < 768) {
        const int which = b >> 8, r = b & 255, h = r >> 4;
        dt = r & 15;
        src = (which == 0 ? qw : which == 1 ? kw : vw) + ((size_t)h * D + dt * 64) * E;
        rs = E;
        if (which == 0)      { dh = wBh; dl = wBl; orow0 = h * 64;        has_lo = true; }
        else if (which == 1) { dh = wBh; dl = wBl; orow0 = 1024 + h * 64; has_lo = true; }
        else                 { dh = wvt; dl = wBl; orow0 = h * 64;        has_lo = false; }
    } else {
        const int r = b - 768, ct = r >> 4;
        dt = r & 15;
        src = ow + (size_t)(dt * 64) * D + ct * 64;
        rs = D;
        orow0 = ct * 64;
        dh = woh; dl = wBl; has_lo = false;   // o: hi only
    }
    {
        const int row = t >> 2, cb = (t & 3) * 16;
        #pragma unroll
        for (int j = 0; j < 16; j += 4) {
            const float4 v = *(const float4*)&src[row * rs + cb + j];
            ts[row][cb + j + 0] = v.x;
            ts[row][cb + j + 1] = v.y;
            ts[row][cb + j + 2] = v.z;
            ts[row][cb + j + 3] = v.w;
        }
    }
    __syncthreads();
    {
        const int cl = t >> 2, dp = (t & 3) * 16;
        bf16x8 hv0, hv1, lv0, lv1;
        #pragma unroll
        for (int i = 0; i < 16; ++i) {
            const float f = ts[dp + i][cl];
            const unsigned short hh = f2bf(f);
            const unsigned short lo = f2bf(f - bf2f(hh));
            if (i < 8) { hv0[i] = (short)hh; lv0[i] = (short)lo; }
            else       { hv1[i - 8] = (short)hh; lv1[i - 8] = (short)lo; }
        }
        const size_t o = (size_t)(orow0 + cl) * D + dt * 64 + dp;
        *(bf16x8*)&dh[o] = hv0;
        *(bf16x8*)&dh[o + 8] = hv1;
        if (has_lo) {
            *(bf16x8*)&dl[o] = lv0;
            *(bf16x8*)&dl[o + 8] = lv1;
        }
    }
}

// ---------------------------------------------------------------------------
// K2: QKV projection (proven 161.5us config, R7-exact). grid (16, 48).
// Tile 128 rows x 64 cols, BK=64, DMA-staged. [0,16)=Q, [16,32)=K, [32,48)=V.
// Q scale folds 1/sqrt(64) AND log2(e): scores come out in log2 domain so
// attn softmax uses bare v_exp_f32 with no per-element multiply.
// ---------------------------------------------------------------------------
__global__ __launch_bounds__(256, 3) void qkv_kernel(
    const unsigned short* __restrict__ xh, const unsigned short* __restrict__ xl,
    const unsigned short* __restrict__ wBh, const unsigned short* __restrict__ wBl,
    const unsigned short* __restrict__ wvt,
    unsigned short* __restrict__ Qh, unsigned short* __restrict__ Ql,
    unsigned short* __restrict__ Kh, unsigned short* __restrict__ Kl,
    unsigned short* __restrict__ Vt)
{
    __shared__ unsigned short ash[128 * 64], asl[128 * 64];
    __shared__ unsigned short bsh[64 * 64], bsl[64 * 64];
    const int n0 = blockIdx.x * 128;
    const int ct0 = blockIdx.y;
    const int sec = ct0 >> 4;            // 0=Q 1=K 2=V
    const int hh = ct0 & 15;
    const bool isv = (sec == 2);
    const unsigned short* Bh = isv ? wvt : wBh;
    const size_t brow0 = (sec == 1 ? 1024 : 0) + hh * 64;

    const int t = threadIdx.x;
    const int lane = t & 63, wvi = t >> 6, quad = lane >> 4, l15 = lane & 15;

    f32x4 acc[2][4];
    #pragma unroll
    for (int i = 0; i < 2; ++i)
        #pragma unroll
        for (int j = 0; j < 4; ++j) acc[i][j] = (f32x4){0.f, 0.f, 0.f, 0.f};

    for (int k0 = 0; k0 < D; k0 += 64) {
        __syncthreads();
        #pragma unroll
        for (int p = 0; p < 4; ++p) {
            const int row = p * 32 + wvi * 8 + (lane >> 3);
            const int lc = (lane & 7) ^ (row & 7);
            const int lo = p * 2048 + wvi * 512 + lane * 8;
            const size_t ga = (size_t)(n0 + row) * D + k0 + lc * 8;
            dma16(&xh[ga], &ash[lo]);
            if (!isv) dma16(&xl[ga], &asl[lo]);
        }
        #pragma unroll
        for (int p = 0; p < 2; ++p) {
            const int row = p * 32 + wvi * 8 + (lane >> 3);
            const int lc = (lane & 7) ^ (row & 7);
            const int lo = p * 2048 + wvi * 512 + lane * 8;
            const size_t gb = (brow0 + row) * D + k0 + lc * 8;
            dma16(&Bh[gb], &bsh[lo]);
            if (!isv) dma16(&wBl[gb], &bsl[lo]);
        }
        __syncthreads();

        #pragma unroll
        for (int kwi = 0; kwi < 2; ++kwi) {
            const int c = kwi * 4 + quad;
            bf16x8 ah[2], al[2], bh[4], bl[4];
            #pragma unroll
            for (int i = 0; i < 2; ++i) {
                ah[i] = *(const bf16x8*)&ash[sw8(wvi * 32 + i * 16 + l15, c)];
                if (!isv) al[i] = *(const bf16x8*)&asl[sw8(wvi * 32 + i * 16 + l15, c)];
            }
            #pragma unroll
            for (int j = 0; j < 4; ++j) {
                bh[j] = *(const bf16x8*)&bsh[sw8(j * 16 + l15, c)];
                if (!isv) bl[j] = *(const bf16x8*)&bsl[sw8(j * 16 + l15, c)];
            }
            #pragma unroll
            for (int i = 0; i < 2; ++i)
                #pragma unroll
                for (int j = 0; j < 4; ++j) {
                    acc[i][j] = MFMA(ah[i], bh[j], acc[i][j]);
                    if (!isv) {
                        acc[i][j] = MFMA(ah[i], bl[j], acc[i][j]);
                        acc[i][j] = MFMA(al[i], bh[j], acc[i][j]);
                    }
                }
        }
    }

    if (isv) {
        #pragma unroll
        for (int j = 0; j < 4; ++j) {
            const int e = j * 16 + l15;
            #pragma unroll
            for (int i = 0; i < 2; ++i) {
                const int nb = n0 + wvi * 32 + i * 16 + quad * 4;
                ushort4 pk;
                pk.x = f2bf(acc[i][j][0]);
                pk.y = f2bf(acc[i][j][1]);
                pk.z = f2bf(acc[i][j][2]);
                pk.w = f2bf(acc[i][j][3]);
                *(ushort4*)&Vt[((size_t)hh * 64 + e) * N + nb] = pk;
            }
        }
    } else {
        // Q: 1/sqrt(64) * log2(e) = 0.125 * 1.4426950408889634
        const float scale = (sec == 0) ? 0.18033688011112042f : 1.0f;
        unsigned short* Oh = (sec == 0) ? Qh : Kh;
        unsigned short* Ol = (sec == 0) ? Ql : Kl;
        #pragma unroll
        for (int j = 0; j < 4; ++j) {
            const int e = j * 16 + l15;
            #pragma unroll
            for (int i = 0; i < 2; ++i)
                #pragma unroll
                for (int r = 0; r < 4; ++r) {
                    const int n = n0 + wvi * 32 + i * 16 + quad * 4 + r;
                    const float val = acc[i][j][r] * scale;
                    const unsigned short hv = f2bf(val);
                    Oh[((size_t)hh * N + n) * E + e] = hv;
                    Ol[((size_t)hh * N + n) * E + e] = f2bf(val - bf2f(hv));
                }
        }
    }
}

// ---------------------------------------------------------------------------
// K3: flash attention (proven KVBLK=128 config + setprio + exact defer-max +
// log2-domain softmax via bare v_exp_f32) + ISOLATED XCD-chunked swizzle:
// 512 flat blocks, sid=(bid&7)*64+(bid>>3) -> each XCD owns 4 contiguous
// (head,split) combos (~2.5MB K/V/Q working set, L2-resident; R4 evidence:
// FETCH 53MB -> 21MB with this mapping). Swapped-QK^T, in-register P,
// psi-permuted reg-staged V. Unnormalized O + (m,l) partials.
// ---------------------------------------------------------------------------
__global__ __launch_bounds__(256, 2) void attn_kernel(
    const unsigned short* __restrict__ Qh, const unsigned short* __restrict__ Ql,
    const unsigned short* __restrict__ Kh, const unsigned short* __restrict__ Kl,
    const unsigned short* __restrict__ Vt,
    unsigned short* __restrict__ Op0, unsigned short* __restrict__ Op1,
    float* __restrict__ mlp)
{
    __shared__ unsigned short kbuf[2 * 16384];   // [buf][ksh 8192 | ksl 8192] shorts
    __shared__ unsigned short vts[64 * 128];     // psi-permuted V tile [e][m-slot]
    const int bid = blockIdx.x;
    const int sid = (bid & 7) * 64 + (bid >> 3);    // bijective: 512 = 8*64
    const int r0 = (sid & 15) * 128;
    const int combo = sid >> 4;
    const int h = combo >> 1, split = combo & 1;
    const int mb = split * 1024;
    const int t = threadIdx.x, lane = t & 63, wvi = t >> 6, quad = lane >> 4, l15 = lane & 15;

    // Q fragments: per-lane content works as MFMA B-operand (col=l15 -> q-row)
    bf16x8 qfh[2][2], qfl[2][2];
    #pragma unroll
    for (int i = 0; i < 2; ++i) {
        const size_t base = ((size_t)h * N + r0 + wvi * 32 + i * 16 + l15) * E;
        #pragma unroll
        for (int kwi = 0; kwi < 2; ++kwi) {
            qfh[i][kwi] = *(const bf16x8*)&Qh[base + kwi * 32 + quad * 8];
            qfl[i][kwi] = *(const bf16x8*)&Ql[base + kwi * 32 + quad * 8];
        }
    }

    // O^T accumulators: col=l15=q (group i), row=quad*4+r -> e=ct*16+quad*4+r
    f32x4 oacc[2][4];
    float mrow[2] = {-1e30f, -1e30f}, lrow[2] = {0.f, 0.f};
    #pragma unroll
    for (int i = 0; i < 2; ++i)
        #pragma unroll
        for (int j = 0; j < 4; ++j) oacc[i][j] = (f32x4){0.f, 0.f, 0.f, 0.f};

    // V staging map: thread covers e = wvi*16 + (lane>>2), c16 = (lane&3)*4 + z
    const int ve = wvi * 16 + (lane >> 2);
    const int vc = lane & 3;

    // prologue: stage K tile 0 into buf 0
    #pragma unroll
    for (int p = 0; p < 4; ++p) {
        const int row = p * 32 + wvi * 8 + (lane >> 3);
        const int lc = (lane & 7) ^ (row & 7);
        const int lo = p * 2048 + wvi * 512 + lane * 8;
        const size_t gk = ((size_t)h * N + mb + row) * E + lc * 8;
        dma16(&Kh[gk], &kbuf[lo]);
        dma16(&Kl[gk], &kbuf[8192 + lo]);
    }

    for (int it = 0; it < 8; ++it) {
        const int cur = it & 1;
        // K[it] landed (vmcnt drain at barrier); vts free (PV of it-1 done)
        __syncthreads();
        const int mcol = mb + it * 128;

        // V -> regs early (psi-permuted 8B pairs); consumed at vts write below
        uint2 vr0[4], vr1[4];
        #pragma unroll
        for (int z = 0; z < 4; ++z) {
            const size_t gb = ((size_t)h * 64 + ve) * N + mcol + vc * 32 + z * 4;
            vr0[z] = *(const uint2*)&Vt[gb];
            vr1[z] = *(const uint2*)&Vt[gb + 16];
        }

        const unsigned short* ksh = &kbuf[cur * 16384];
        const unsigned short* ksl = ksh + 8192;

        // QK^T swapped: s[i][ct] = S^T (log2 domain), rows m=ct*16+quad*4+r
        f32x4 s[2][8];
        #pragma unroll
        for (int i = 0; i < 2; ++i)
            #pragma unroll
            for (int ct = 0; ct < 8; ++ct) s[i][ct] = (f32x4){0.f, 0.f, 0.f, 0.f};

        __builtin_amdgcn_s_setprio(1);
        #pragma unroll
        for (int kwi = 0; kwi < 2; ++kwi) {
            const int c = kwi * 4 + quad;
            #pragma unroll
            for (int ct = 0; ct < 8; ++ct) {
                const bf16x8 kh = *(const bf16x8*)&ksh[sw8(ct * 16 + l15, c)];
                const bf16x8 kl = *(const bf16x8*)&ksl[sw8(ct * 16 + l15, c)];
                #pragma unroll
                for (int i = 0; i < 2; ++i) {
                    s[i][ct] = MFMA(kh, qfh[i][kwi], s[i][ct]);
                    s[i][ct] = MFMA(kl, qfh[i][kwi], s[i][ct]);
                    s[i][ct] = MFMA(kh, qfl[i][kwi], s[i][ct]);
                }
            }
        }
        __builtin_amdgcn_s_setprio(0);

        // online softmax (log2 domain, bare v_exp_f32): lane owns q-row (i,l15)
        #pragma unroll
        for (int i = 0; i < 2; ++i) {
            float m0 = s[i][0][0], m1 = s[i][0][1], m2 = s[i][0][2], m3 = s[i][0][3];
            #pragma unroll
            for (int ct = 1; ct < 8; ++ct) {
                m0 = fmaxf(m0, s[i][ct][0]); m1 = fmaxf(m1, s[i][ct][1]);
                m2 = fmaxf(m2, s[i][ct][2]); m3 = fmaxf(m3, s[i][ct][3]);
            }
            float mx = fmaxf(fmaxf(m0, m1), fmaxf(m2, m3));
            mx = fmaxf(mx, __shfl_xor(mx, 16));
            mx = fmaxf(mx, __shfl_xor(mx, 32));
            // exact defer-max: alpha==1 when no lane's max grew -> skip rescale
            if (__any(mx > mrow[i])) {
                const float mn = fmaxf(mrow[i], mx);
                const float al = ex2(mrow[i] - mn);
                mrow[i] = mn;
                lrow[i] *= al;
                #pragma unroll
                for (int ct = 0; ct < 4; ++ct) {
                    oacc[i][ct][0] *= al; oacc[i][ct][1] *= al;
                    oacc[i][ct][2] *= al; oacc[i][ct][3] *= al;
                }
            }
            const float mn = mrow[i];
            float s0 = 0.f, s1 = 0.f, s2 = 0.f, s3 = 0.f;
            #pragma unroll
            for (int ct = 0; ct < 8; ++ct) {
                const float p0 = ex2(s[i][ct][0] - mn);
                const float p1 = ex2(s[i][ct][1] - mn);
                const float p2 = ex2(s[i][ct][2] - mn);
                const float p3 = ex2(s[i][ct][3] - mn);
                s[i][ct][0] = p0; s[i][ct][1] = p1;
                s[i][ct][2] = p2; s[i][ct][3] = p3;
                s0 += p0; s1 += p1; s2 += p2; s3 += p3;
            }
            float sum = (s0 + s1) + (s2 + s3);
            sum += __shfl_xor(sum, 16);
            sum += __shfl_xor(sum, 32);
            lrow[i] += sum;
        }

        // write V tile: phys chunk c16 ^ (e&7); slots p=c16*8+u hold
        // V[m0 + (c16>>2)*32 + (u>>2)*16 + (c16&3)*4 + (u&3)][e]
        #pragma unroll
        for (int z = 0; z < 4; ++z) {
            const int c16 = vc * 4 + z;
            u32x4 w = (u32x4){vr0[z].x, vr0[z].y, vr1[z].x, vr1[z].y};
            *(u32x4*)&vts[ve * 128 + ((c16 ^ (ve & 7)) << 3)] = w;
        }
        __syncthreads();

        // prefetch K[it+1] (overlaps PV; drained at next top barrier)
        if (it < 7) {
            #pragma unroll
            for (int p = 0; p < 4; ++p) {
                const int row = p * 32 + wvi * 8 + (lane >> 3);
                const int lc = (lane & 7) ^ (row & 7);
                const int lo = (cur ^ 1) * 16384 + p * 2048 + wvi * 512 + lane * 8;
                const size_t gk = ((size_t)h * N + mcol + 128 + row) * E + lc * 8;
                dma16(&Kh[gk], &kbuf[lo]);
                dma16(&Kl[gk], &kbuf[8192 + lo]);
            }
        }

        // PV: O^T += V^T(A) * P^T(B); B built in-register, zero LDS for P
        #pragma unroll
        for (int kb = 0; kb < 4; ++kb) {
            bf16x8 pb[2];
            #pragma unroll
            for (int i = 0; i < 2; ++i)
                pb[i] = pk4(cvtpk(s[i][2 * kb][0],     s[i][2 * kb][1]),
                            cvtpk(s[i][2 * kb][2],     s[i][2 * kb][3]),
                            cvtpk(s[i][2 * kb + 1][0], s[i][2 * kb + 1][1]),
                            cvtpk(s[i][2 * kb + 1][2], s[i][2 * kb + 1][3]));
            __builtin_amdgcn_s_setprio(1);
            #pragma unroll
            for (int ct = 0; ct < 4; ++ct) {
                const int re = ct * 16 + l15;
                const bf16x8 va =
                    *(const bf16x8*)&vts[re * 128 + (((kb * 4 + quad) ^ (re & 7)) << 3)];
                #pragma unroll
                for (int i = 0; i < 2; ++i)
                    oacc[i][ct] = MFMA(va, pb[i], oacc[i][ct]);
            }
            __builtin_amdgcn_s_setprio(0);
        }
    }

    // epilogue: unnormalized O (bf16) + (m,l) partials (m in log2 domain)
    unsigned short* Opc = split ? Op1 : Op0;
    #pragma unroll
    for (int i = 0; i < 2; ++i) {
        const int n = r0 + wvi * 32 + i * 16 + l15;
        if (quad == 0) {
            mlp[(((size_t)split * 16 + h) * 2048 + n) * 2 + 0] = mrow[i];
            mlp[(((size_t)split * 16 + h) * 2048 + n) * 2 + 1] = lrow[i];
        }
        #pragma unroll
        for (int ct = 0; ct < 4; ++ct) {
            ushort4 pk;
            pk.x = f2bf(oacc[i][ct][0]);
            pk.y = f2bf(oacc[i][ct][1]);
            pk.z = f2bf(oacc[i][ct][2]);
            pk.w = f2bf(oacc[i][ct][3]);
            *(ushort4*)&Opc[((size_t)h * 2048 + n) * 64 + ct * 16 + quad * 4] = pk;
        }
    }
}

// ---------------------------------------------------------------------------
// K3b: combine the two KV-split partials into Ch (log2-domain m). grid (32,16).
// ---------------------------------------------------------------------------
__global__ __launch_bounds__(256) void combine_kernel(
    const unsigned short* __restrict__ Op0, const unsigned short* __restrict__ Op1,
    const float* __restrict__ mlp, unsigned short* __restrict__ Ch)
{
    const int h = blockIdx.y;
    const int n = blockIdx.x * 64 + (threadIdx.x >> 2);
    const int e0 = (threadIdx.x & 3) * 16;
    const float m0 = mlp[((size_t)h * 2048 + n) * 2 + 0];
    const float l0 = mlp[((size_t)h * 2048 + n) * 2 + 1];
    const float m1 = mlp[((size_t)(16 + h) * 2048 + n) * 2 + 0];
    const float l1 = mlp[((size_t)(16 + h) * 2048 + n) * 2 + 1];
    const float M = fmaxf(m0, m1);
    const float a0 = ex2(m0 - M), a1 = ex2(m1 - M);
    const float inv = 1.f / (l0 * a0 + l1 * a1);
    const size_t ib = ((size_t)h * 2048 + n) * 64 + e0;
    const size_t ob = (size_t)n * D + h * 64 + e0;
    #pragma unroll
    for (int j = 0; j < 2; ++j) {
        const bf16x8 v0 = *(const bf16x8*)&Op0[ib + j * 8];
        const bf16x8 v1 = *(const bf16x8*)&Op1[ib + j * 8];
        bf16x8 o;
        #pragma unroll
        for (int k = 0; k < 8; ++k) {
            const float c = (bf2f((unsigned short)v0[k]) * a0 +
                             bf2f((unsigned short)v1[k]) * a1) * inv;
            o[k] = (short)f2bf(c);
        }
        *(bf16x8*)&Ch[ob + j * 8] = o;
    }
}

// ---------------------------------------------------------------------------
// K4: out = ctx @ Wo, single-term bf16. grid (32, 16); tile 64x64, BK=128
// (half the barrier drains of BK=64; LDS 32KB, still 4 blocks/CU).
// ---------------------------------------------------------------------------
__global__ __launch_bounds__(256, 4) void out_proj_kernel(
    const unsigned short* __restrict__ Chh, const unsigned short* __restrict__ Wh,
    float* __restrict__ out)
{
    __shared__ unsigned short ash[64 * 128], bsh[64 * 128];
    const int n0 = blockIdx.x * 64, c0 = blockIdx.y * 64;
    const int t = threadIdx.x, lane = t & 63, wvi = t >> 6, quad = lane >> 4, l15 = lane & 15;

    f32x4 acc[4];
    #pragma unroll
    for (int j = 0; j < 4; ++j) acc[j] = (f32x4){0.f, 0.f, 0.f, 0.f};

    for (int k0 = 0; k0 < D; k0 += 128) {
        __syncthreads();
        // stage 64x128 A and B tiles: thread covers row=p*16+wvi*4+quad,
        // chunk=l15 (16 chunks of 8 shorts per row), XOR-swizzled source col.
        #pragma unroll
        for (int p = 0; p < 4; ++p) {
            const int row = p * 16 + wvi * 4 + quad;
            const int lc = l15 ^ (row & 7);
            const int lo = p * 2048 + wvi * 512 + lane * 8;
            dma16(&Chh[(size_t)(n0 + row) * D + k0 + lc * 8], &ash[lo]);
            dma16(&Wh[(size_t)(c0 + row) * D + k0 + lc * 8], &bsh[lo]);
        }
        __syncthreads();

        #pragma unroll
        for (int kwi = 0; kwi < 4; ++kwi) {
            const int c = kwi * 4 + quad;
            const bf16x8 ah = *(const bf16x8*)&ash[sw16(wvi * 16 + l15, c)];
            #pragma unroll
            for (int j = 0; j < 4; ++j) {
                const bf16x8 bh = *(const bf16x8*)&bsh[sw16(j * 16 + l15, c)];
                acc[j] = MFMA(ah, bh, acc[j]);
            }
        }
    }

    #pragma unroll
    for (int r = 0; r < 4; ++r) {
        const int n = n0 + wvi * 16 + quad * 4 + r;
        #pragma unroll
        for (int j = 0; j < 4; ++j)
            out[(size_t)n * D + c0 + j * 16 + l15] = acc[j][r];
    }
}

// ---------------------------------------------------------------------------
extern "C" void kernel_launch(void* const* d_in, const int* in_sizes, int n_in,
                              void* d_out, int out_size, void* d_ws, size_t ws_size,
                              hipStream_t stream) {
    const float* x  = (const float*)d_in[0];
    const float* qw = (const float*)d_in[1];
    const float* kw = (const float*)d_in[2];
    const float* vw = (const float*)d_in[3];
    const float* ow = (const float*)d_in[4];
    float* out = (float*)d_out;

    unsigned short* ws = (unsigned short*)d_ws;
    const size_t M1 = 1024 * 1024;
    unsigned short* wBh = ws;                 // [2048][1024] = 2M shorts
    unsigned short* wBl = ws + 2 * M1;
    unsigned short* wvt = ws + 4 * M1;        // [1024][1024] = 1M
    unsigned short* woh = ws + 5 * M1;
    unsigned short* xh  = ws + 6 * M1;        // [2048][1024] = 2M
    unsigned short* xl  = ws + 8 * M1;
    unsigned short* Qh  = ws + 10 * M1;       // [h][n][e] = 2M each
    unsigned short* Ql  = ws + 12 * M1;
    unsigned short* Kh  = ws + 14 * M1;
    unsigned short* Kl  = ws + 16 * M1;
    unsigned short* Vt  = ws + 18 * M1;       // [h*64+e][n] = 2M
    unsigned short* Ch  = xh;                 // alias: x dead after qkv

    // attn partials reuse regions dead after qkv:
    unsigned short* Op0 = wBh;                // [16][2048][64] bf16 = 2M shorts
    unsigned short* Op1 = wBl;                // [16][2048][64] bf16 = 2M shorts
    float* mlp = (float*)wvt;                 // [2][16][2048][2] f32 = 512KB

    convert_all_kernel<<<3072, 256, 0, stream>>>(x, qw, kw, vw, ow,
                                                 xh, xl, wBh, wBl, wvt, woh);
    qkv_kernel<<<dim3(16, 48), 256, 0, stream>>>(xh, xl, wBh, wBl, wvt,
                                                 Qh, Ql, Kh, Kl, Vt);
    attn_kernel<<<512, 256, 0, stream>>>(Qh, Ql, Kh, Kl, Vt, Op0, Op1, mlp);
    combine_kernel<<<dim3(32, 16), 256, 0, stream>>>(Op0, Op1, mlp, Ch);
    out_proj_kernel<<<dim3(32, 16), 256, 0, stream>>>(Ch, woh, out);
}

// Round 15
// 158.553 us; speedup vs baseline: 1.0332x; 1.0181x over previous
//
#include <hip/hip_runtime.h>

#define H 16
#define N 2048
#define E 64
#define D 1024

typedef __attribute__((ext_vector_type(8))) short bf16x8;
typedef __attribute__((ext_vector_type(4))) float f32x4;
typedef __attribute__((ext_vector_type(4))) unsigned int u32x4;

__device__ __forceinline__ float bf2f(unsigned short u) {
    union { unsigned int i; float f; } v;
    v.i = ((unsigned int)u) << 16;
    return v.f;
}
__device__ __forceinline__ unsigned short f2bf(float f) {
    unsigned int u = __float_as_uint(f);
    return (unsigned short)((u + 0x7fffu + ((u >> 16) & 1u)) >> 16);
}
// v_cvt_pk_bf16_f32: D.lo = bf16(lo), D.hi = bf16(hi)
__device__ __forceinline__ unsigned int cvtpk(float lo, float hi) {
    unsigned int r;
    asm("v_cvt_pk_bf16_f32 %0, %1, %2" : "=v"(r) : "v"(lo), "v"(hi));
    return r;
}
__device__ __forceinline__ bf16x8 pk4(unsigned int a, unsigned int b,
                                      unsigned int c, unsigned int d) {
    union { u32x4 u; bf16x8 h; } x;
    x.u = (u32x4){a, b, c, d};
    return x.h;
}
// bare hardware exp2: v_exp_f32 computes D = 2^S0 (one transcendental op;
// exp2f() would lower to the precise OCML routine, ~6 ops -- measured R6)
__device__ __forceinline__ float ex2(float x) {
    float r;
    asm("v_exp_f32 %0, %1" : "=v"(r) : "v"(x));
    return r;
}
#define MFMA(a, b, c) __builtin_amdgcn_mfma_f32_16x16x32_bf16(a, b, c, 0, 0, 0)

// async global->LDS, 16B per lane. LDS dest must be base+lane*16 contiguous.
typedef __attribute__((address_space(3))) unsigned int lds_u32;
typedef const __attribute__((address_space(1))) unsigned int glb_u32;
__device__ __forceinline__ void dma16(const unsigned short* g, unsigned short* l) {
    __builtin_amdgcn_global_load_lds((glb_u32*)g, (lds_u32*)l, 16, 0, 0);
}

// XOR-swizzled LDS tiles (16B chunk granularity): physical chunk = c ^ (row&7).
__device__ __forceinline__ int sw8(int row, int c)  { return row * 64  + ((c ^ (row & 7)) << 3); }
__device__ __forceinline__ int sw16(int row, int c) { return row * 128 + ((c ^ (row & 7)) << 3); }

// ---------------------------------------------------------------------------
// K1: merged converts. blocks [0,2048): x fp32 -> xh/xl.
// blocks [2048,3072): weights. q -> wBh/wBl rows [0,1024); k -> rows
// [1024,2048); v -> wvt [h*64+e][d] (hi only); o -> woh [c][d] (hi only).
// ---------------------------------------------------------------------------
__global__ __launch_bounds__(256) void convert_all_kernel(
    const float* __restrict__ x,
    const float* __restrict__ qw, const float* __restrict__ kw,
    const float* __restrict__ vw, const float* __restrict__ ow,
    unsigned short* __restrict__ xh, unsigned short* __restrict__ xl,
    unsigned short* __restrict__ wBh, unsigned short* __restrict__ wBl,
    unsigned short* __restrict__ wvt, unsigned short* __restrict__ woh)
{
    __shared__ float ts[64][65];
    const int b0 = blockIdx.x;
    const int t = threadIdx.x;
    if (b0 < 2048) {
        const int i = (b0 * 256 + t) * 4;
        const float4 v = *(const float4*)&x[i];
        ushort4 hh, ll;
        hh.x = f2bf(v.x); ll.x = f2bf(v.x - bf2f(hh.x));
        hh.y = f2bf(v.y); ll.y = f2bf(v.y - bf2f(hh.y));
        hh.z = f2bf(v.z); ll.z = f2bf(v.z - bf2f(hh.z));
        hh.w = f2bf(v.w); ll.w = f2bf(v.w - bf2f(hh.w));
        *(ushort4*)&xh[i] = hh;
        *(ushort4*)&xl[i] = ll;
        return;
    }
    const int b = b0 - 2048;
    const float* src;
    int rs, dt, orow0;
    bool has_lo;
    unsigned short *dh, *dl;
    if (b < 768) {
        const int which = b >> 8, r = b & 255, h = r >> 4;
        dt = r & 15;
        src = (which == 0 ? qw : which == 1 ? kw : vw) + ((size_t)h * D + dt * 64) * E;
        rs = E;
        if (which == 0)      { dh = wBh; dl = wBl; orow0 = h * 64;        has_lo = true; }
        else if (which == 1) { dh = wBh; dl = wBl; orow0 = 1024 + h * 64; has_lo = true; }
        else                 { dh = wvt; dl = wBl; orow0 = h * 64;        has_lo = false; }
    } else {
        const int r = b - 768, ct = r >> 4;
        dt = r & 15;
        src = ow + (size_t)(dt * 64) * D + ct * 64;
        rs = D;
        orow0 = ct * 64;
        dh = woh; dl = wBl; has_lo = false;   // o: hi only
    }
    {
        const int row = t >> 2, cb = (t & 3) * 16;
        #pragma unroll
        for (int j = 0; j < 16; j += 4) {
            const float4 v = *(const float4*)&src[row * rs + cb + j];
            ts[row][cb + j + 0] = v.x;
            ts[row][cb + j + 1] = v.y;
            ts[row][cb + j + 2] = v.z;
            ts[row][cb + j + 3] = v.w;
        }
    }
    __syncthreads();
    {
        const int cl = t >> 2, dp = (t & 3) * 16;
        bf16x8 hv0, hv1, lv0, lv1;
        #pragma unroll
        for (int i = 0; i < 16; ++i) {
            const float f = ts[dp + i][cl];
            const unsigned short hh = f2bf(f);
            const unsigned short lo = f2bf(f - bf2f(hh));
            if (i < 8) { hv0[i] = (short)hh; lv0[i] = (short)lo; }
            else       { hv1[i - 8] = (short)hh; lv1[i - 8] = (short)lo; }
        }
        const size_t o = (size_t)(orow0 + cl) * D + dt * 64 + dp;
        *(bf16x8*)&dh[o] = hv0;
        *(bf16x8*)&dh[o + 8] = hv1;
        if (has_lo) {
            *(bf16x8*)&dl[o] = lv0;
            *(bf16x8*)&dl[o + 8] = lv1;
        }
    }
}

// ---------------------------------------------------------------------------
// K2: QKV projection (proven best config, R7-exact). grid (16, 48).
// Tile 128 rows x 64 cols, BK=64, DMA-staged. [0,16)=Q, [16,32)=K, [32,48)=V.
// Q scale folds 1/sqrt(64) AND log2(e): scores come out in log2 domain so
// attn softmax uses bare v_exp_f32 with no per-element multiply.
// ---------------------------------------------------------------------------
__global__ __launch_bounds__(256, 3) void qkv_kernel(
    const unsigned short* __restrict__ xh, const unsigned short* __restrict__ xl,
    const unsigned short* __restrict__ wBh, const unsigned short* __restrict__ wBl,
    const unsigned short* __restrict__ wvt,
    unsigned short* __restrict__ Qh, unsigned short* __restrict__ Ql,
    unsigned short* __restrict__ Kh, unsigned short* __restrict__ Kl,
    unsigned short* __restrict__ Vt)
{
    __shared__ unsigned short ash[128 * 64], asl[128 * 64];
    __shared__ unsigned short bsh[64 * 64], bsl[64 * 64];
    const int n0 = blockIdx.x * 128;
    const int ct0 = blockIdx.y;
    const int sec = ct0 >> 4;            // 0=Q 1=K 2=V
    const int hh = ct0 & 15;
    const bool isv = (sec == 2);
    const unsigned short* Bh = isv ? wvt : wBh;
    const size_t brow0 = (sec == 1 ? 1024 : 0) + hh * 64;

    const int t = threadIdx.x;
    const int lane = t & 63, wvi = t >> 6, quad = lane >> 4, l15 = lane & 15;

    f32x4 acc[2][4];
    #pragma unroll
    for (int i = 0; i < 2; ++i)
        #pragma unroll
        for (int j = 0; j < 4; ++j) acc[i][j] = (f32x4){0.f, 0.f, 0.f, 0.f};

    for (int k0 = 0; k0 < D; k0 += 64) {
        __syncthreads();
        #pragma unroll
        for (int p = 0; p < 4; ++p) {
            const int row = p * 32 + wvi * 8 + (lane >> 3);
            const int lc = (lane & 7) ^ (row & 7);
            const int lo = p * 2048 + wvi * 512 + lane * 8;
            const size_t ga = (size_t)(n0 + row) * D + k0 + lc * 8;
            dma16(&xh[ga], &ash[lo]);
            if (!isv) dma16(&xl[ga], &asl[lo]);
        }
        #pragma unroll
        for (int p = 0; p < 2; ++p) {
            const int row = p * 32 + wvi * 8 + (lane >> 3);
            const int lc = (lane & 7) ^ (row & 7);
            const int lo = p * 2048 + wvi * 512 + lane * 8;
            const size_t gb = (brow0 + row) * D + k0 + lc * 8;
            dma16(&Bh[gb], &bsh[lo]);
            if (!isv) dma16(&wBl[gb], &bsl[lo]);
        }
        __syncthreads();

        #pragma unroll
        for (int kwi = 0; kwi < 2; ++kwi) {
            const int c = kwi * 4 + quad;
            bf16x8 ah[2], al[2], bh[4], bl[4];
            #pragma unroll
            for (int i = 0; i < 2; ++i) {
                ah[i] = *(const bf16x8*)&ash[sw8(wvi * 32 + i * 16 + l15, c)];
                if (!isv) al[i] = *(const bf16x8*)&asl[sw8(wvi * 32 + i * 16 + l15, c)];
            }
            #pragma unroll
            for (int j = 0; j < 4; ++j) {
                bh[j] = *(const bf16x8*)&bsh[sw8(j * 16 + l15, c)];
                if (!isv) bl[j] = *(const bf16x8*)&bsl[sw8(j * 16 + l15, c)];
            }
            #pragma unroll
            for (int i = 0; i < 2; ++i)
                #pragma unroll
                for (int j = 0; j < 4; ++j) {
                    acc[i][j] = MFMA(ah[i], bh[j], acc[i][j]);
                    if (!isv) {
                        acc[i][j] = MFMA(ah[i], bl[j], acc[i][j]);
                        acc[i][j] = MFMA(al[i], bh[j], acc[i][j]);
                    }
                }
        }
    }

    if (isv) {
        #pragma unroll
        for (int j = 0; j < 4; ++j) {
            const int e = j * 16 + l15;
            #pragma unroll
            for (int i = 0; i < 2; ++i) {
                const int nb = n0 + wvi * 32 + i * 16 + quad * 4;
                ushort4 pk;
                pk.x = f2bf(acc[i][j][0]);
                pk.y = f2bf(acc[i][j][1]);
                pk.z = f2bf(acc[i][j][2]);
                pk.w = f2bf(acc[i][j][3]);
                *(ushort4*)&Vt[((size_t)hh * 64 + e) * N + nb] = pk;
            }
        }
    } else {
        // Q: 1/sqrt(64) * log2(e) = 0.125 * 1.4426950408889634
        const float scale = (sec == 0) ? 0.18033688011112042f : 1.0f;
        unsigned short* Oh = (sec == 0) ? Qh : Kh;
        unsigned short* Ol = (sec == 0) ? Ql : Kl;
        #pragma unroll
        for (int j = 0; j < 4; ++j) {
            const int e = j * 16 + l15;
            #pragma unroll
            for (int i = 0; i < 2; ++i)
                #pragma unroll
                for (int r = 0; r < 4; ++r) {
                    const int n = n0 + wvi * 32 + i * 16 + quad * 4 + r;
                    const float val = acc[i][j][r] * scale;
                    const unsigned short hv = f2bf(val);
                    Oh[((size_t)hh * N + n) * E + e] = hv;
                    Ol[((size_t)hh * N + n) * E + e] = f2bf(val - bf2f(hv));
                }
        }
    }
}

// ---------------------------------------------------------------------------
// K3: flash attention (proven KVBLK=128 config + setprio + exact defer-max +
// log2-domain softmax via bare v_exp_f32). Swapped-QK^T (S^T = K*Q^T) so
// softmax is lane-local; in-register P via cvt_pk; psi-permuted reg-staged V.
// grid (16 q-tiles, 16 heads, 2 KV-splits); unnormalized O + (m,l) partials.
// ---------------------------------------------------------------------------
__global__ __launch_bounds__(256, 2) void attn_kernel(
    const unsigned short* __restrict__ Qh, const unsigned short* __restrict__ Ql,
    const unsigned short* __restrict__ Kh, const unsigned short* __restrict__ Kl,
    const unsigned short* __restrict__ Vt,
    unsigned short* __restrict__ Op0, unsigned short* __restrict__ Op1,
    float* __restrict__ mlp)
{
    __shared__ unsigned short kbuf[2 * 16384];   // [buf][ksh 8192 | ksl 8192] shorts
    __shared__ unsigned short vts[64 * 128];     // psi-permuted V tile [e][m-slot]
    const int r0 = blockIdx.x * 128, h = blockIdx.y, split = blockIdx.z;
    const int mb = split * 1024;
    const int t = threadIdx.x, lane = t & 63, wvi = t >> 6, quad = lane >> 4, l15 = lane & 15;

    // Q fragments: per-lane content works as MFMA B-operand (col=l15 -> q-row)
    bf16x8 qfh[2][2], qfl[2][2];
    #pragma unroll
    for (int i = 0; i < 2; ++i) {
        const size_t base = ((size_t)h * N + r0 + wvi * 32 + i * 16 + l15) * E;
        #pragma unroll
        for (int kwi = 0; kwi < 2; ++kwi) {
            qfh[i][kwi] = *(const bf16x8*)&Qh[base + kwi * 32 + quad * 8];
            qfl[i][kwi] = *(const bf16x8*)&Ql[base + kwi * 32 + quad * 8];
        }
    }

    // O^T accumulators: col=l15=q (group i), row=quad*4+r -> e=ct*16+quad*4+r
    f32x4 oacc[2][4];
    float mrow[2] = {-1e30f, -1e30f}, lrow[2] = {0.f, 0.f};
    #pragma unroll
    for (int i = 0; i < 2; ++i)
        #pragma unroll
        for (int j = 0; j < 4; ++j) oacc[i][j] = (f32x4){0.f, 0.f, 0.f, 0.f};

    // V staging map: thread covers e = wvi*16 + (lane>>2), c16 = (lane&3)*4 + z
    const int ve = wvi * 16 + (lane >> 2);
    const int vc = lane & 3;

    // prologue: stage K tile 0 into buf 0
    #pragma unroll
    for (int p = 0; p < 4; ++p) {
        const int row = p * 32 + wvi * 8 + (lane >> 3);
        const int lc = (lane & 7) ^ (row & 7);
        const int lo = p * 2048 + wvi * 512 + lane * 8;
        const size_t gk = ((size_t)h * N + mb + row) * E + lc * 8;
        dma16(&Kh[gk], &kbuf[lo]);
        dma16(&Kl[gk], &kbuf[8192 + lo]);
    }

    for (int it = 0; it < 8; ++it) {
        const int cur = it & 1;
        // K[it] landed (vmcnt drain at barrier); vts free (PV of it-1 done)
        __syncthreads();
        const int mcol = mb + it * 128;

        // V -> regs early (psi-permuted 8B pairs); consumed at vts write below
        uint2 vr0[4], vr1[4];
        #pragma unroll
        for (int z = 0; z < 4; ++z) {
            const size_t gb = ((size_t)h * 64 + ve) * N + mcol + vc * 32 + z * 4;
            vr0[z] = *(const uint2*)&Vt[gb];
            vr1[z] = *(const uint2*)&Vt[gb + 16];
        }

        const unsigned short* ksh = &kbuf[cur * 16384];
        const unsigned short* ksl = ksh + 8192;

        // QK^T swapped: s[i][ct] = S^T (log2 domain), rows m=ct*16+quad*4+r
        f32x4 s[2][8];
        #pragma unroll
        for (int i = 0; i < 2; ++i)
            #pragma unroll
            for (int ct = 0; ct < 8; ++ct) s[i][ct] = (f32x4){0.f, 0.f, 0.f, 0.f};

        __builtin_amdgcn_s_setprio(1);
        #pragma unroll
        for (int kwi = 0; kwi < 2; ++kwi) {
            const int c = kwi * 4 + quad;
            #pragma unroll
            for (int ct = 0; ct < 8; ++ct) {
                const bf16x8 kh = *(const bf16x8*)&ksh[sw8(ct * 16 + l15, c)];
                const bf16x8 kl = *(const bf16x8*)&ksl[sw8(ct * 16 + l15, c)];
                #pragma unroll
                for (int i = 0; i < 2; ++i) {
                    s[i][ct] = MFMA(kh, qfh[i][kwi], s[i][ct]);
                    s[i][ct] = MFMA(kl, qfh[i][kwi], s[i][ct]);
                    s[i][ct] = MFMA(kh, qfl[i][kwi], s[i][ct]);
                }
            }
        }
        __builtin_amdgcn_s_setprio(0);

        // online softmax (log2 domain, bare v_exp_f32): lane owns q-row (i,l15)
        #pragma unroll
        for (int i = 0; i < 2; ++i) {
            float m0 = s[i][0][0], m1 = s[i][0][1], m2 = s[i][0][2], m3 = s[i][0][3];
            #pragma unroll
            for (int ct = 1; ct < 8; ++ct) {
                m0 = fmaxf(m0, s[i][ct][0]); m1 = fmaxf(m1, s[i][ct][1]);
                m2 = fmaxf(m2, s[i][ct][2]); m3 = fmaxf(m3, s[i][ct][3]);
            }
            float mx = fmaxf(fmaxf(m0, m1), fmaxf(m2, m3));
            mx = fmaxf(mx, __shfl_xor(mx, 16));
            mx = fmaxf(mx, __shfl_xor(mx, 32));
            // exact defer-max: alpha==1 when no lane's max grew -> skip rescale
            if (__any(mx > mrow[i])) {
                const float mn = fmaxf(mrow[i], mx);
                const float al = ex2(mrow[i] - mn);
                mrow[i] = mn;
                lrow[i] *= al;
                #pragma unroll
                for (int ct = 0; ct < 4; ++ct) {
                    oacc[i][ct][0] *= al; oacc[i][ct][1] *= al;
                    oacc[i][ct][2] *= al; oacc[i][ct][3] *= al;
                }
            }
            const float mn = mrow[i];
            float s0 = 0.f, s1 = 0.f, s2 = 0.f, s3 = 0.f;
            #pragma unroll
            for (int ct = 0; ct < 8; ++ct) {
                const float p0 = ex2(s[i][ct][0] - mn);
                const float p1 = ex2(s[i][ct][1] - mn);
                const float p2 = ex2(s[i][ct][2] - mn);
                const float p3 = ex2(s[i][ct][3] - mn);
                s[i][ct][0] = p0; s[i][ct][1] = p1;
                s[i][ct][2] = p2; s[i][ct][3] = p3;
                s0 += p0; s1 += p1; s2 += p2; s3 += p3;
            }
            float sum = (s0 + s1) + (s2 + s3);
            sum += __shfl_xor(sum, 16);
            sum += __shfl_xor(sum, 32);
            lrow[i] += sum;
        }

        // write V tile: phys chunk c16 ^ (e&7); slots p=c16*8+u hold
        // V[m0 + (c16>>2)*32 + (u>>2)*16 + (c16&3)*4 + (u&3)][e]
        #pragma unroll
        for (int z = 0; z < 4; ++z) {
            const int c16 = vc * 4 + z;
            u32x4 w = (u32x4){vr0[z].x, vr0[z].y, vr1[z].x, vr1[z].y};
            *(u32x4*)&vts[ve * 128 + ((c16 ^ (ve & 7)) << 3)] = w;
        }
        __syncthreads();

        // prefetch K[it+1] (overlaps PV; drained at next top barrier)
        if (it < 7) {
            #pragma unroll
            for (int p = 0; p < 4; ++p) {
                const int row = p * 32 + wvi * 8 + (lane >> 3);
                const int lc = (lane & 7) ^ (row & 7);
                const int lo = (cur ^ 1) * 16384 + p * 2048 + wvi * 512 + lane * 8;
                const size_t gk = ((size_t)h * N + mcol + 128 + row) * E + lc * 8;
                dma16(&Kh[gk], &kbuf[lo]);
                dma16(&Kl[gk], &kbuf[8192 + lo]);
            }
        }

        // PV: O^T += V^T(A) * P^T(B); B built in-register, zero LDS for P
        #pragma unroll
        for (int kb = 0; kb < 4; ++kb) {
            bf16x8 pb[2];
            #pragma unroll
            for (int i = 0; i < 2; ++i)
                pb[i] = pk4(cvtpk(s[i][2 * kb][0],     s[i][2 * kb][1]),
                            cvtpk(s[i][2 * kb][2],     s[i][2 * kb][3]),
                            cvtpk(s[i][2 * kb + 1][0], s[i][2 * kb + 1][1]),
                            cvtpk(s[i][2 * kb + 1][2], s[i][2 * kb + 1][3]));
            __builtin_amdgcn_s_setprio(1);
            #pragma unroll
            for (int ct = 0; ct < 4; ++ct) {
                const int re = ct * 16 + l15;
                const bf16x8 va =
                    *(const bf16x8*)&vts[re * 128 + (((kb * 4 + quad) ^ (re & 7)) << 3)];
                #pragma unroll
                for (int i = 0; i < 2; ++i)
                    oacc[i][ct] = MFMA(va, pb[i], oacc[i][ct]);
            }
            __builtin_amdgcn_s_setprio(0);
        }
    }

    // epilogue: unnormalized O (bf16) + (m,l) partials (m in log2 domain)
    unsigned short* Opc = split ? Op1 : Op0;
    #pragma unroll
    for (int i = 0; i < 2; ++i) {
        const int n = r0 + wvi * 32 + i * 16 + l15;
        if (quad == 0) {
            mlp[(((size_t)split * 16 + h) * 2048 + n) * 2 + 0] = mrow[i];
            mlp[(((size_t)split * 16 + h) * 2048 + n) * 2 + 1] = lrow[i];
        }
        #pragma unroll
        for (int ct = 0; ct < 4; ++ct) {
            ushort4 pk;
            pk.x = f2bf(oacc[i][ct][0]);
            pk.y = f2bf(oacc[i][ct][1]);
            pk.z = f2bf(oacc[i][ct][2]);
            pk.w = f2bf(oacc[i][ct][3]);
            *(ushort4*)&Opc[((size_t)h * 2048 + n) * 64 + ct * 16 + quad * 4] = pk;
        }
    }
}

// ---------------------------------------------------------------------------
// K3b: combine the two KV-split partials into Ch (log2-domain m). grid (32,16).
// ---------------------------------------------------------------------------
__global__ __launch_bounds__(256) void combine_kernel(
    const unsigned short* __restrict__ Op0, const unsigned short* __restrict__ Op1,
    const float* __restrict__ mlp, unsigned short* __restrict__ Ch)
{
    const int h = blockIdx.y;
    const int n = blockIdx.x * 64 + (threadIdx.x >> 2);
    const int e0 = (threadIdx.x & 3) * 16;
    const float m0 = mlp[((size_t)h * 2048 + n) * 2 + 0];
    const float l0 = mlp[((size_t)h * 2048 + n) * 2 + 1];
    const float m1 = mlp[((size_t)(16 + h) * 2048 + n) * 2 + 0];
    const float l1 = mlp[((size_t)(16 + h) * 2048 + n) * 2 + 1];
    const float M = fmaxf(m0, m1);
    const float a0 = ex2(m0 - M), a1 = ex2(m1 - M);
    const float inv = 1.f / (l0 * a0 + l1 * a1);
    const size_t ib = ((size_t)h * 2048 + n) * 64 + e0;
    const size_t ob = (size_t)n * D + h * 64 + e0;
    #pragma unroll
    for (int j = 0; j < 2; ++j) {
        const bf16x8 v0 = *(const bf16x8*)&Op0[ib + j * 8];
        const bf16x8 v1 = *(const bf16x8*)&Op1[ib + j * 8];
        bf16x8 o;
        #pragma unroll
        for (int k = 0; k < 8; ++k) {
            const float c = (bf2f((unsigned short)v0[k]) * a0 +
                             bf2f((unsigned short)v1[k]) * a1) * inv;
            o[k] = (short)f2bf(c);
        }
        *(bf16x8*)&Ch[ob + j * 8] = o;
    }
}

// ---------------------------------------------------------------------------
// K4: out = ctx @ Wo, single-term bf16. grid (32, 16); tile 64x64, BK=128
// (half the barrier drains of BK=64; LDS 32KB, still 4 blocks/CU).
// ---------------------------------------------------------------------------
__global__ __launch_bounds__(256, 4) void out_proj_kernel(
    const unsigned short* __restrict__ Chh, const unsigned short* __restrict__ Wh,
    float* __restrict__ out)
{
    __shared__ unsigned short ash[64 * 128], bsh[64 * 128];
    const int n0 = blockIdx.x * 64, c0 = blockIdx.y * 64;
    const int t = threadIdx.x, lane = t & 63, wvi = t >> 6, quad = lane >> 4, l15 = lane & 15;

    f32x4 acc[4];
    #pragma unroll
    for (int j = 0; j < 4; ++j) acc[j] = (f32x4){0.f, 0.f, 0.f, 0.f};

    for (int k0 = 0; k0 < D; k0 += 128) {
        __syncthreads();
        // stage 64x128 A and B tiles: thread covers row=p*16+wvi*4+quad,
        // chunk=l15 (16 chunks of 8 shorts per row), XOR-swizzled source col.
        #pragma unroll
        for (int p = 0; p < 4; ++p) {
            const int row = p * 16 + wvi * 4 + quad;
            const int lc = l15 ^ (row & 7);
            const int lo = p * 2048 + wvi * 512 + lane * 8;
            dma16(&Chh[(size_t)(n0 + row) * D + k0 + lc * 8], &ash[lo]);
            dma16(&Wh[(size_t)(c0 + row) * D + k0 + lc * 8], &bsh[lo]);
        }
        __syncthreads();

        #pragma unroll
        for (int kwi = 0; kwi < 4; ++kwi) {
            const int c = kwi * 4 + quad;
            const bf16x8 ah = *(const bf16x8*)&ash[sw16(wvi * 16 + l15, c)];
            #pragma unroll
            for (int j = 0; j < 4; ++j) {
                const bf16x8 bh = *(const bf16x8*)&bsh[sw16(j * 16 + l15, c)];
                acc[j] = MFMA(ah, bh, acc[j]);
            }
        }
    }

    #pragma unroll
    for (int r = 0; r < 4; ++r) {
        const int n = n0 + wvi * 16 + quad * 4 + r;
        #pragma unroll
        for (int j = 0; j < 4; ++j)
            out[(size_t)n * D + c0 + j * 16 + l15] = acc[j][r];
    }
}

// ---------------------------------------------------------------------------
extern "C" void kernel_launch(void* const* d_in, const int* in_sizes, int n_in,
                              void* d_out, int out_size, void* d_ws, size_t ws_size,
                              hipStream_t stream) {
    const float* x  = (const float*)d_in[0];
    const float* qw = (const float*)d_in[1];
    const float* kw = (const float*)d_in[2];
    const float* vw = (const float*)d_in[3];
    const float* ow = (const float*)d_in[4];
    float* out = (float*)d_out;

    unsigned short* ws = (unsigned short*)d_ws;
    const size_t M1 = 1024 * 1024;
    unsigned short* wBh = ws;                 // [2048][1024] = 2M shorts
    unsigned short* wBl = ws + 2 * M1;
    unsigned short* wvt = ws + 4 * M1;        // [1024][1024] = 1M
    unsigned short* woh = ws + 5 * M1;
    unsigned short* xh  = ws + 6 * M1;        // [2048][1024] = 2M
    unsigned short* xl  = ws + 8 * M1;
    unsigned short* Qh  = ws + 10 * M1;       // [h][n][e] = 2M each
    unsigned short* Ql  = ws + 12 * M1;
    unsigned short* Kh  = ws + 14 * M1;
    unsigned short* Kl  = ws + 16 * M1;
    unsigned short* Vt  = ws + 18 * M1;       // [h*64+e][n] = 2M
    unsigned short* Ch  = xh;                 // alias: x dead after qkv

    // attn partials reuse regions dead after qkv:
    unsigned short* Op0 = wBh;                // [16][2048][64] bf16 = 2M shorts
    unsigned short* Op1 = wBl;                // [16][2048][64] bf16 = 2M shorts
    float* mlp = (float*)wvt;                 // [2][16][2048][2] f32 = 512KB

    convert_all_kernel<<<3072, 256, 0, stream>>>(x, qw, kw, vw, ow,
                                                 xh, xl, wBh, wBl, wvt, woh);
    qkv_kernel<<<dim3(16, 48), 256, 0, stream>>>(xh, xl, wBh, wBl, wvt,
                                                 Qh, Ql, Kh, Kl, Vt);
    attn_kernel<<<dim3(16, 16, 2), 256, 0, stream>>>(Qh, Ql, Kh, Kl, Vt,
                                                     Op0, Op1, mlp);
    combine_kernel<<<dim3(32, 16), 256, 0, stream>>>(Op0, Op1, mlp, Ch);
    out_proj_kernel<<<dim3(32, 16), 256, 0, stream>>>(Ch, woh, out);
}